// Round 1
// baseline (2775.813 us; speedup 1.0000x reference)
//
#include <hip/hip_runtime.h>
#include <math.h>

// Problem constants
#define DIM   320
#define HD    40
#define NH    8
#define LQ    2048
#define BATCH 2
#define MROWS (BATCH*LQ)   // 4096
#define FFD   1280
#define FF2   2560         // 2*FFD

// ---------------- LayerNorm: one wave per row of 320 ----------------
__global__ __launch_bounds__(256) void ln_kernel(
    const float* __restrict__ X, const float* __restrict__ g,
    const float* __restrict__ bta, float* __restrict__ Y)
{
  int row  = blockIdx.x * 4 + (threadIdx.x >> 6);
  int lane = threadIdx.x & 63;
  const float* x = X + (size_t)row * DIM;
  float v[5];
  float s = 0.f;
#pragma unroll
  for (int i = 0; i < 5; ++i) { v[i] = x[lane + 64*i]; s += v[i]; }
#pragma unroll
  for (int off = 32; off >= 1; off >>= 1) s += __shfl_xor(s, off, 64);
  float mean = s * (1.0f/DIM);
  float sq = 0.f;
#pragma unroll
  for (int i = 0; i < 5; ++i) { float d = v[i] - mean; sq += d*d; }
#pragma unroll
  for (int off = 32; off >= 1; off >>= 1) sq += __shfl_xor(sq, off, 64);
  float rstd = rsqrtf(sq*(1.0f/DIM) + 1e-5f);
  float* y = Y + (size_t)row * DIM;
#pragma unroll
  for (int i = 0; i < 5; ++i) {
    int c = lane + 64*i;
    y[c] = (v[i]-mean)*rstd*g[c] + bta[c];
  }
}

// ---------------- Tiled fp32 GEMM: C[M,N] = A[M,K(lda)] @ W[K,N(ldw)] (+bias)(+R) --
#define BM 64
#define BN 64
#define BK 16

__global__ __launch_bounds__(256) void gemm_kernel(
    const float* __restrict__ A, int lda,
    const float* __restrict__ W, int ldw,
    const float* __restrict__ bias,   // [N] or nullptr
    const float* __restrict__ R,      // residual [M,ldc] or nullptr
    float* __restrict__ C, int ldc,
    int M, int N, int K)
{
  __shared__ float As[BK][BM+4];   // +4 pad: keeps 16B align, breaks store conflicts
  __shared__ float Bs[BK][BN];
  int tid = threadIdx.x;
  int bm = blockIdx.y * BM;
  int bn = blockIdx.x * BN;
  // A-tile load mapping: 64 rows x 16 k, float4 per thread
  int ar = tid >> 2;            // 0..63
  int ac = (tid & 3) << 2;      // 0,4,8,12
  // W-tile load mapping: 16 k-rows x 64 n, float4 per thread
  int br = tid >> 4;            // 0..15
  int bc = (tid & 15) << 2;     // 0..60
  int tx = tid & 15, ty = tid >> 4;

  float acc[4][4];
#pragma unroll
  for (int i = 0; i < 4; ++i)
#pragma unroll
    for (int j = 0; j < 4; ++j) acc[i][j] = 0.f;

  const float* Aptr = A + (size_t)(bm + ar)*lda + ac;
  const float* Wptr = W + (size_t)br*ldw + bn + bc;

  for (int k0 = 0; k0 < K; k0 += BK) {
    float4 a4 = *(const float4*)(Aptr + k0);
    float4 b4 = *(const float4*)(Wptr + (size_t)k0*ldw);
    As[ac+0][ar] = a4.x; As[ac+1][ar] = a4.y;
    As[ac+2][ar] = a4.z; As[ac+3][ar] = a4.w;
    *(float4*)&Bs[br][bc] = b4;
    __syncthreads();
#pragma unroll
    for (int kk = 0; kk < BK; ++kk) {
      float4 av = *(const float4*)&As[kk][ty << 2];
      float4 bv = *(const float4*)&Bs[kk][tx << 2];
      float am[4] = {av.x, av.y, av.z, av.w};
      float bb[4] = {bv.x, bv.y, bv.z, bv.w};
#pragma unroll
      for (int i = 0; i < 4; ++i)
#pragma unroll
        for (int j = 0; j < 4; ++j)
          acc[i][j] = fmaf(am[i], bb[j], acc[i][j]);
    }
    __syncthreads();
  }

#pragma unroll
  for (int i = 0; i < 4; ++i) {
    int r = bm + (ty << 2) + i;
#pragma unroll
    for (int j = 0; j < 4; ++j) {
      int c = bn + (tx << 2) + j;
      float val = acc[i][j];
      if (bias) val += bias[c];
      if (R)    val += R[(size_t)r*ldc + c];
      C[(size_t)r*ldc + c] = val;
    }
  }
}

// ---------------- Self-attention: one wave per query row, online softmax ----
__global__ __launch_bounds__(256) void attn_kernel(
    const float* __restrict__ Q, const float* __restrict__ K,
    const float* __restrict__ V, float* __restrict__ O)
{
  const float scale = 0.15811388300841897f;  // 1/sqrt(40)
  int wave = blockIdx.x * 4 + (threadIdx.x >> 6);
  int lane = threadIdx.x & 63;
  int qi = wave & (LQ-1);
  int bh = wave >> 11;            // 0..15
  int b = bh >> 3, h = bh & 7;

  const float* qrow = Q + (size_t)(b*LQ + qi)*DIM + h*HD;
  float qv[HD];
#pragma unroll
  for (int t = 0; t < 10; ++t) {
    float4 f = *(const float4*)(qrow + 4*t);
    qv[4*t] = f.x; qv[4*t+1] = f.y; qv[4*t+2] = f.z; qv[4*t+3] = f.w;
  }
  const float* Kb = K + (size_t)b*LQ*DIM + h*HD;
  const float* Vb = V + (size_t)b*LQ*DIM + h*HD;

  float m = -1e30f, l = 0.f;
  float acc[HD];
#pragma unroll
  for (int d = 0; d < HD; ++d) acc[d] = 0.f;

  for (int i = 0; i < LQ/64; ++i) {
    int kk = (i << 6) + lane;
    const float* kr = Kb + (size_t)kk*DIM;
    float tv[HD];
#pragma unroll
    for (int t = 0; t < 10; ++t) {
      float4 f = *(const float4*)(kr + 4*t);
      tv[4*t] = f.x; tv[4*t+1] = f.y; tv[4*t+2] = f.z; tv[4*t+3] = f.w;
    }
    float s = 0.f;
#pragma unroll
    for (int d = 0; d < HD; ++d) s = fmaf(qv[d], tv[d], s);
    s *= scale;
    float mn = fmaxf(m, s);
    float co = __expf(m - mn);
    float p  = __expf(s - mn);
    l = l*co + p;
    const float* vr = Vb + (size_t)kk*DIM;
#pragma unroll
    for (int t = 0; t < 10; ++t) {
      float4 f = *(const float4*)(vr + 4*t);
      tv[4*t] = f.x; tv[4*t+1] = f.y; tv[4*t+2] = f.z; tv[4*t+3] = f.w;
    }
#pragma unroll
    for (int d = 0; d < HD; ++d) acc[d] = acc[d]*co + p*tv[d];
    m = mn;
  }

  // Butterfly merge of (m, l, acc[40]) across the 64 lanes
#pragma unroll
  for (int off = 32; off >= 1; off >>= 1) {
    float m2 = __shfl_xor(m, off, 64);
    float l2 = __shfl_xor(l, off, 64);
    float mn = fmaxf(m, m2);
    float c1 = __expf(m - mn), c2 = __expf(m2 - mn);
    l = l*c1 + l2*c2;
#pragma unroll
    for (int d = 0; d < HD; ++d)
      acc[d] = acc[d]*c1 + __shfl_xor(acc[d], off, 64)*c2;
    m = mn;
  }

  if (lane < HD) {
    O[(size_t)(b*LQ + qi)*DIM + h*HD + lane] = acc[lane] / l;
  }
}

// ---------------- GEGLU: proj[:, :1280] *= gelu_exact(proj[:, 1280:]) -------
__global__ __launch_bounds__(256) void geglu_kernel(float* __restrict__ proj)
{
  int idx = blockIdx.x * 256 + threadIdx.x;    // over MROWS * (FFD/4)
  int mrow = idx / (FFD/4);
  int j4   = idx - mrow*(FFD/4);
  float4* px = (float4*)(proj + (size_t)mrow*FF2) + j4;
  float4* pg = (float4*)(proj + (size_t)mrow*FF2 + FFD) + j4;
  float4 x = *px, g = *pg;
  const float k = 0.7071067811865476f;
  x.x *= 0.5f * g.x * (1.f + erff(g.x * k));
  x.y *= 0.5f * g.y * (1.f + erff(g.y * k));
  x.z *= 0.5f * g.z * (1.f + erff(g.z * k));
  x.w *= 0.5f * g.w * (1.f + erff(g.w * k));
  *px = x;
}

extern "C" void kernel_launch(void* const* d_in, const int* in_sizes, int n_in,
                              void* d_out, int out_size, void* d_ws, size_t ws_size,
                              hipStream_t stream) {
  const float* hidden = (const float*)d_in[0];
  // d_in[1] encoder_hidden_states: UNUSED (softmax rows sum to 1 -> cross == vH)
  const float* ln1_g = (const float*)d_in[2];
  const float* ln1_b = (const float*)d_in[3];
  const float* wq1   = (const float*)d_in[4];
  const float* wk1   = (const float*)d_in[5];
  const float* wv1   = (const float*)d_in[6];
  const float* wo1   = (const float*)d_in[7];
  const float* bo1   = (const float*)d_in[8];
  const float* ln2_g = (const float*)d_in[9];
  const float* ln2_b = (const float*)d_in[10];
  // d_in[11] wq2, d_in[12] wk2: UNUSED
  const float* wvh   = (const float*)d_in[13];
  const float* wo2   = (const float*)d_in[14];
  const float* bo2   = (const float*)d_in[15];
  const float* ln3_g = (const float*)d_in[16];
  const float* ln3_b = (const float*)d_in[17];
  const float* wff1  = (const float*)d_in[18];
  const float* bff1  = (const float*)d_in[19];
  const float* wff2  = (const float*)d_in[20];
  const float* bff2  = (const float*)d_in[21];
  float* out = (float*)d_out;

  float* ws = (float*)d_ws;
  const size_t NB = (size_t)MROWS * DIM;   // 1,310,720 floats
  float* buf0 = ws;            // ln out / attn out / ln3 out
  float* buf1 = buf0 + NB;     // q / ln2 out
  float* buf2 = buf1 + NB;     // k
  float* buf3 = buf2 + NB;     // v
  float* h1   = buf3 + NB;     // hidden after stage 1
  float* h2   = h1   + NB;     // hidden after stage 2
  float* Wc   = h2   + NB;     // wvh @ wo2, 320x320
  float* proj = Wc + (size_t)DIM*DIM;  // 4096 x 2560

  dim3 t256(256);
  dim3 g320(DIM/BN, MROWS/BM);   // (5, 64)
  dim3 gwc(DIM/BN, DIM/BM);      // (5, 5)
  dim3 gff1(FF2/BN, MROWS/BM);   // (40, 64)

  // Stage 1: self-attention
  ln_kernel<<<MROWS/4, t256, 0, stream>>>(hidden, ln1_g, ln1_b, buf0);
  gemm_kernel<<<g320, t256, 0, stream>>>(buf0, DIM, wq1, DIM, nullptr, nullptr, buf1, DIM, MROWS, DIM, DIM);
  gemm_kernel<<<g320, t256, 0, stream>>>(buf0, DIM, wk1, DIM, nullptr, nullptr, buf2, DIM, MROWS, DIM, DIM);
  gemm_kernel<<<g320, t256, 0, stream>>>(buf0, DIM, wv1, DIM, nullptr, nullptr, buf3, DIM, MROWS, DIM, DIM);
  attn_kernel<<<(BATCH*NH*LQ)/4, t256, 0, stream>>>(buf1, buf2, buf3, buf0);
  gemm_kernel<<<g320, t256, 0, stream>>>(buf0, DIM, wo1, DIM, bo1, hidden, h1, DIM, MROWS, DIM, DIM);

  // Stage 2: "cross-attention" == ln2(h1) @ (wvh @ wo2) + bo2 (softmax sums to 1)
  ln_kernel<<<MROWS/4, t256, 0, stream>>>(h1, ln2_g, ln2_b, buf1);
  gemm_kernel<<<gwc,  t256, 0, stream>>>(wvh, DIM, wo2, DIM, nullptr, nullptr, Wc, DIM, DIM, DIM, DIM);
  gemm_kernel<<<g320, t256, 0, stream>>>(buf1, DIM, Wc, DIM, bo2, h1, h2, DIM, MROWS, DIM, DIM);

  // Stage 3: GEGLU FF
  ln_kernel<<<MROWS/4, t256, 0, stream>>>(h2, ln3_g, ln3_b, buf0);
  gemm_kernel<<<gff1, t256, 0, stream>>>(buf0, DIM, wff1, FF2, bff1, nullptr, proj, FF2, MROWS, FF2, DIM);
  geglu_kernel<<<(MROWS*(FFD/4))/256, t256, 0, stream>>>(proj);
  gemm_kernel<<<g320, t256, 0, stream>>>(proj, FF2, wff2, DIM, bff2, h2, out, DIM, MROWS, DIM, FFD);
}

// Round 2
// 881.366 us; speedup vs baseline: 3.1494x; 3.1494x over previous
//
#include <hip/hip_runtime.h>
#include <math.h>

// Problem constants
#define DIM   320
#define HD    40
#define NH    8
#define LQ    2048
#define BATCH 2
#define MROWS (BATCH*LQ)   // 4096
#define FFD   1280
#define FF2   2560         // 2*FFD

#define KSPLIT 4
#define KCHUNK (LQ/KSPLIT) // 512
#define KTILE  32
#define NQROWS (BATCH*NH*LQ)  // 32768 total q rows across b,h

// ---------------- LayerNorm: one wave per row of 320 ----------------
__global__ __launch_bounds__(256) void ln_kernel(
    const float* __restrict__ X, const float* __restrict__ g,
    const float* __restrict__ bta, float* __restrict__ Y)
{
  int row  = blockIdx.x * 4 + (threadIdx.x >> 6);
  int lane = threadIdx.x & 63;
  const float* x = X + (size_t)row * DIM;
  float v[5];
  float s = 0.f;
#pragma unroll
  for (int i = 0; i < 5; ++i) { v[i] = x[lane + 64*i]; s += v[i]; }
#pragma unroll
  for (int off = 32; off >= 1; off >>= 1) s += __shfl_xor(s, off, 64);
  float mean = s * (1.0f/DIM);
  float sq = 0.f;
#pragma unroll
  for (int i = 0; i < 5; ++i) { float d = v[i] - mean; sq += d*d; }
#pragma unroll
  for (int off = 32; off >= 1; off >>= 1) sq += __shfl_xor(sq, off, 64);
  float rstd = rsqrtf(sq*(1.0f/DIM) + 1e-5f);
  float* y = Y + (size_t)row * DIM;
#pragma unroll
  for (int i = 0; i < 5; ++i) {
    int c = lane + 64*i;
    y[c] = (v[i]-mean)*rstd*g[c] + bta[c];
  }
}

// ---------------- Tiled fp32 GEMM: C[M,N] = A[M,K(lda)] @ W[K,N(ldw)] (+bias)(+R) --
#define BM 64
#define BN 64
#define BK 16

__global__ __launch_bounds__(256) void gemm_kernel(
    const float* __restrict__ A, int lda,
    const float* __restrict__ W, int ldw,
    const float* __restrict__ bias,   // [N] or nullptr
    const float* __restrict__ R,      // residual [M,ldc] or nullptr
    float* __restrict__ C, int ldc,
    int M, int N, int K)
{
  __shared__ float As[BK][BM+4];
  __shared__ float Bs[BK][BN];
  int tid = threadIdx.x;
  int bm = blockIdx.y * BM;
  int bn = blockIdx.x * BN;
  int ar = tid >> 2;            // 0..63
  int ac = (tid & 3) << 2;      // 0,4,8,12
  int br = tid >> 4;            // 0..15
  int bc = (tid & 15) << 2;     // 0..60
  int tx = tid & 15, ty = tid >> 4;

  float acc[4][4];
#pragma unroll
  for (int i = 0; i < 4; ++i)
#pragma unroll
    for (int j = 0; j < 4; ++j) acc[i][j] = 0.f;

  const float* Aptr = A + (size_t)(bm + ar)*lda + ac;
  const float* Wptr = W + (size_t)br*ldw + bn + bc;

  for (int k0 = 0; k0 < K; k0 += BK) {
    float4 a4 = *(const float4*)(Aptr + k0);
    float4 b4 = *(const float4*)(Wptr + (size_t)k0*ldw);
    As[ac+0][ar] = a4.x; As[ac+1][ar] = a4.y;
    As[ac+2][ar] = a4.z; As[ac+3][ar] = a4.w;
    *(float4*)&Bs[br][bc] = b4;
    __syncthreads();
#pragma unroll
    for (int kk = 0; kk < BK; ++kk) {
      float4 av = *(const float4*)&As[kk][ty << 2];
      float4 bv = *(const float4*)&Bs[kk][tx << 2];
      float am[4] = {av.x, av.y, av.z, av.w};
      float bb[4] = {bv.x, bv.y, bv.z, bv.w};
#pragma unroll
      for (int i = 0; i < 4; ++i)
#pragma unroll
        for (int j = 0; j < 4; ++j)
          acc[i][j] = fmaf(am[i], bb[j], acc[i][j]);
    }
    __syncthreads();
  }

#pragma unroll
  for (int i = 0; i < 4; ++i) {
    int r = bm + (ty << 2) + i;
#pragma unroll
    for (int j = 0; j < 4; ++j) {
      int c = bn + (tx << 2) + j;
      float val = acc[i][j];
      if (bias) val += bias[c];
      if (R)    val += R[(size_t)r*ldc + c];
      C[(size_t)r*ldc + c] = val;
    }
  }
}

// ---------------- Flash attention, k-split partials ----------------
// Grid: (LQ/64, 16 bh, KSPLIT); block 64 threads, thread-per-qrow.
// All per-row state in statically-indexed registers (no scratch spill).
__global__ __launch_bounds__(64, 4) void attn_flash(
    const float* __restrict__ Q, const float* __restrict__ K,
    const float* __restrict__ V,
    float* __restrict__ Pm, float* __restrict__ Pl, float* __restrict__ Pacc)
{
  __shared__ float Ks[KTILE*40];
  __shared__ float Vs[KTILE*40];
  int tid = threadIdx.x;
  int qt  = blockIdx.x;
  int bh  = blockIdx.y;
  int ks  = blockIdx.z;
  int b = bh >> 3, h = bh & 7;
  int qi = qt*64 + tid;

  // scale * log2(e): softmax in base 2
  const float lscale = 0.15811388300841897f * 1.4426950408889634f;
  const float* qrow = Q + (size_t)(b*LQ + qi)*DIM + h*HD;
  float q[40];
#pragma unroll
  for (int t = 0; t < 10; ++t) {
    float4 f = *((const float4*)qrow + t);
    q[4*t]   = f.x*lscale; q[4*t+1] = f.y*lscale;
    q[4*t+2] = f.z*lscale; q[4*t+3] = f.w*lscale;
  }
  const float* Kb = K + (size_t)b*LQ*DIM + h*HD;
  const float* Vb = V + (size_t)b*LQ*DIM + h*HD;
  int k0base = ks*KCHUNK;

  float m = -1e30f, l = 0.f;
  float acc[40];
#pragma unroll
  for (int d = 0; d < 40; ++d) acc[d] = 0.f;

  for (int t0 = 0; t0 < KCHUNK; t0 += KTILE) {
    __syncthreads();
    // stage KTILE rows of K and V (40 floats each) into LDS, coalesced
#pragma unroll
    for (int i = 0; i < 5; ++i) {
      int f = i*64 + tid;        // 0..319 = 32 rows x 10 float4
      int r = f / 10, c = f - 10*r;
      size_t roff = (size_t)(k0base + t0 + r)*DIM;
      *(float4*)(Ks + r*40 + c*4) = *((const float4*)(Kb + roff) + c);
      *(float4*)(Vs + r*40 + c*4) = *((const float4*)(Vb + roff) + c);
    }
    __syncthreads();

#pragma unroll
    for (int sub = 0; sub < KTILE/16; ++sub) {
      float s[16];
#pragma unroll
      for (int j = 0; j < 16; ++j) {
        const float4* kr = (const float4*)&Ks[(sub*16+j)*40];
        float t = 0.f;
#pragma unroll
        for (int u = 0; u < 10; ++u) {
          float4 f4 = kr[u];
          t = fmaf(q[4*u],   f4.x, t);
          t = fmaf(q[4*u+1], f4.y, t);
          t = fmaf(q[4*u+2], f4.z, t);
          t = fmaf(q[4*u+3], f4.w, t);
        }
        s[j] = t;
      }
      float tm = s[0];
#pragma unroll
      for (int j = 1; j < 16; ++j) tm = fmaxf(tm, s[j]);
      float mn = fmaxf(m, tm);
      float co = exp2f(m - mn);
      m = mn;
      l *= co;
#pragma unroll
      for (int d = 0; d < 40; ++d) acc[d] *= co;
#pragma unroll
      for (int j = 0; j < 16; ++j) {
        float p = exp2f(s[j] - mn);
        l += p;
        const float4* vr = (const float4*)&Vs[(sub*16+j)*40];
#pragma unroll
        for (int u = 0; u < 10; ++u) {
          float4 f4 = vr[u];
          acc[4*u]   = fmaf(p, f4.x, acc[4*u]);
          acc[4*u+1] = fmaf(p, f4.y, acc[4*u+1]);
          acc[4*u+2] = fmaf(p, f4.z, acc[4*u+2]);
          acc[4*u+3] = fmaf(p, f4.w, acc[4*u+3]);
        }
      }
    }
  }

  size_t gq = (size_t)bh*LQ + qi;          // 0..32767
  size_t pidx = (size_t)ks*NQROWS + gq;
  Pm[pidx] = m;
  Pl[pidx] = l;
  float4* pa = (float4*)(Pacc + pidx*40);
#pragma unroll
  for (int u = 0; u < 10; ++u)
    pa[u] = make_float4(acc[4*u], acc[4*u+1], acc[4*u+2], acc[4*u+3]);
}

// Merge KSPLIT partials per q-row -> O
__global__ __launch_bounds__(256) void attn_merge(
    const float* __restrict__ Pm, const float* __restrict__ Pl,
    const float* __restrict__ Pacc, float* __restrict__ O)
{
  int idx = blockIdx.x*256 + threadIdx.x;   // 0..32767
  int bh = idx >> 11, qi = idx & (LQ-1);
  int b = bh >> 3, h = bh & 7;
  float m[KSPLIT], l[KSPLIT];
  float M = -1e30f;
#pragma unroll
  for (int k = 0; k < KSPLIT; ++k) {
    m[k] = Pm[(size_t)k*NQROWS + idx];
    l[k] = Pl[(size_t)k*NQROWS + idx];
    M = fmaxf(M, m[k]);
  }
  float c[KSPLIT], L = 0.f;
#pragma unroll
  for (int k = 0; k < KSPLIT; ++k) {
    c[k] = exp2f(m[k] - M);
    L += c[k]*l[k];
  }
  float inv = 1.0f / L;
  float* orow = O + (size_t)(b*LQ + qi)*DIM + h*HD;
#pragma unroll
  for (int u = 0; u < 10; ++u) {
    float4 o = make_float4(0.f, 0.f, 0.f, 0.f);
#pragma unroll
    for (int k = 0; k < KSPLIT; ++k) {
      float4 a = *((const float4*)(Pacc + ((size_t)k*NQROWS + idx)*40) + u);
      o.x = fmaf(c[k], a.x, o.x);
      o.y = fmaf(c[k], a.y, o.y);
      o.z = fmaf(c[k], a.z, o.z);
      o.w = fmaf(c[k], a.w, o.w);
    }
    o.x *= inv; o.y *= inv; o.z *= inv; o.w *= inv;
    *((float4*)orow + u) = o;
  }
}

// ---------------- GEGLU: proj[:, :1280] *= gelu_exact(proj[:, 1280:]) -------
__global__ __launch_bounds__(256) void geglu_kernel(float* __restrict__ proj)
{
  int idx = blockIdx.x * 256 + threadIdx.x;    // over MROWS * (FFD/4)
  int mrow = idx / (FFD/4);
  int j4   = idx - mrow*(FFD/4);
  float4* px = (float4*)(proj + (size_t)mrow*FF2) + j4;
  float4* pg = (float4*)(proj + (size_t)mrow*FF2 + FFD) + j4;
  float4 x = *px, g = *pg;
  const float k = 0.7071067811865476f;
  x.x *= 0.5f * g.x * (1.f + erff(g.x * k));
  x.y *= 0.5f * g.y * (1.f + erff(g.y * k));
  x.z *= 0.5f * g.z * (1.f + erff(g.z * k));
  x.w *= 0.5f * g.w * (1.f + erff(g.w * k));
  *px = x;
}

extern "C" void kernel_launch(void* const* d_in, const int* in_sizes, int n_in,
                              void* d_out, int out_size, void* d_ws, size_t ws_size,
                              hipStream_t stream) {
  const float* hidden = (const float*)d_in[0];
  // d_in[1] encoder_hidden_states: UNUSED (softmax rows sum to 1 -> cross == vH)
  const float* ln1_g = (const float*)d_in[2];
  const float* ln1_b = (const float*)d_in[3];
  const float* wq1   = (const float*)d_in[4];
  const float* wk1   = (const float*)d_in[5];
  const float* wv1   = (const float*)d_in[6];
  const float* wo1   = (const float*)d_in[7];
  const float* bo1   = (const float*)d_in[8];
  const float* ln2_g = (const float*)d_in[9];
  const float* ln2_b = (const float*)d_in[10];
  // d_in[11] wq2, d_in[12] wk2: UNUSED
  const float* wvh   = (const float*)d_in[13];
  const float* wo2   = (const float*)d_in[14];
  const float* bo2   = (const float*)d_in[15];
  const float* ln3_g = (const float*)d_in[16];
  const float* ln3_b = (const float*)d_in[17];
  const float* wff1  = (const float*)d_in[18];
  const float* bff1  = (const float*)d_in[19];
  const float* wff2  = (const float*)d_in[20];
  const float* bff2  = (const float*)d_in[21];
  float* out = (float*)d_out;

  float* ws = (float*)d_ws;
  const size_t NB = (size_t)MROWS * DIM;   // 1,310,720 floats
  float* buf0 = ws;            // ln out / attn out / ln3 out
  float* buf1 = buf0 + NB;     // q / ln2 out
  float* buf2 = buf1 + NB;     // k
  float* buf3 = buf2 + NB;     // v
  float* h1   = buf3 + NB;     // hidden after stage 1
  float* h2   = h1   + NB;     // hidden after stage 2
  float* Wc   = h2   + NB;     // wvh @ wo2, 320x320
  float* proj = Wc + (size_t)DIM*DIM;  // 4096 x 2560 (stage 3)

  // Attention k-split partials alias the proj region (disjoint lifetimes):
  float* Pm   = proj;                       // KSPLIT*32768
  float* Pl   = Pm + (size_t)KSPLIT*NQROWS;
  float* Pacc = Pl + (size_t)KSPLIT*NQROWS; // KSPLIT*32768*40

  dim3 t256(256);
  dim3 g320(DIM/BN, MROWS/BM);   // (5, 64)
  dim3 gwc(DIM/BN, DIM/BM);      // (5, 5)
  dim3 gff1(FF2/BN, MROWS/BM);   // (40, 64)
  dim3 gattn(LQ/64, BATCH*NH, KSPLIT);

  // Stage 1: self-attention
  ln_kernel<<<MROWS/4, t256, 0, stream>>>(hidden, ln1_g, ln1_b, buf0);
  gemm_kernel<<<g320, t256, 0, stream>>>(buf0, DIM, wq1, DIM, nullptr, nullptr, buf1, DIM, MROWS, DIM, DIM);
  gemm_kernel<<<g320, t256, 0, stream>>>(buf0, DIM, wk1, DIM, nullptr, nullptr, buf2, DIM, MROWS, DIM, DIM);
  gemm_kernel<<<g320, t256, 0, stream>>>(buf0, DIM, wv1, DIM, nullptr, nullptr, buf3, DIM, MROWS, DIM, DIM);
  attn_flash<<<gattn, dim3(64), 0, stream>>>(buf1, buf2, buf3, Pm, Pl, Pacc);
  attn_merge<<<NQROWS/256, t256, 0, stream>>>(Pm, Pl, Pacc, buf0);
  gemm_kernel<<<g320, t256, 0, stream>>>(buf0, DIM, wo1, DIM, bo1, hidden, h1, DIM, MROWS, DIM, DIM);

  // Stage 2: "cross-attention" == ln2(h1) @ (wvh @ wo2) + bo2 (softmax sums to 1)
  ln_kernel<<<MROWS/4, t256, 0, stream>>>(h1, ln2_g, ln2_b, buf1);
  gemm_kernel<<<gwc,  t256, 0, stream>>>(wvh, DIM, wo2, DIM, nullptr, nullptr, Wc, DIM, DIM, DIM, DIM);
  gemm_kernel<<<g320, t256, 0, stream>>>(buf1, DIM, Wc, DIM, bo2, h1, h2, DIM, MROWS, DIM, DIM);

  // Stage 3: GEGLU FF
  ln_kernel<<<MROWS/4, t256, 0, stream>>>(h2, ln3_g, ln3_b, buf0);
  gemm_kernel<<<gff1, t256, 0, stream>>>(buf0, DIM, wff1, FF2, bff1, nullptr, proj, FF2, MROWS, FF2, DIM);
  geglu_kernel<<<(MROWS*(FFD/4))/256, t256, 0, stream>>>(proj);
  gemm_kernel<<<g320, t256, 0, stream>>>(proj, FF2, wff2, DIM, bff2, h2, out, DIM, MROWS, DIM, FFD);
}

// Round 3
// 546.052 us; speedup vs baseline: 5.0834x; 1.6141x over previous
//
#include <hip/hip_runtime.h>
#include <math.h>

// Problem constants
#define DIM   320
#define HD    40
#define NH    8
#define LQ    2048
#define BATCH 2
#define MROWS (BATCH*LQ)   // 4096
#define FFD   1280
#define FF2   2560         // 2*FFD

#define KSPLIT 2
#define KCHUNK (LQ/KSPLIT) // 1024
#define KT     32          // k-rows per staged tile
#define NQROWS (BATCH*NH*LQ)  // 32768 total q rows across b,h

using bf16x8 = __attribute__((ext_vector_type(8))) short;
using f32x4  = __attribute__((ext_vector_type(4))) float;

static __device__ inline short f2bf(float f) {
  union { float f; unsigned u; } x{f};
  unsigned r = x.u + 0x7FFFu + ((x.u >> 16) & 1u);
  return (short)(r >> 16);
}

// ---------------- LayerNorm: one wave per row of 320 ----------------
__global__ __launch_bounds__(256) void ln_kernel(
    const float* __restrict__ X, const float* __restrict__ g,
    const float* __restrict__ bta, float* __restrict__ Y)
{
  int row  = blockIdx.x * 4 + (threadIdx.x >> 6);
  int lane = threadIdx.x & 63;
  const float* x = X + (size_t)row * DIM;
  float v[5];
  float s = 0.f;
#pragma unroll
  for (int i = 0; i < 5; ++i) { v[i] = x[lane + 64*i]; s += v[i]; }
#pragma unroll
  for (int off = 32; off >= 1; off >>= 1) s += __shfl_xor(s, off, 64);
  float mean = s * (1.0f/DIM);
  float sq = 0.f;
#pragma unroll
  for (int i = 0; i < 5; ++i) { float d = v[i] - mean; sq += d*d; }
#pragma unroll
  for (int off = 32; off >= 1; off >>= 1) sq += __shfl_xor(sq, off, 64);
  float rstd = rsqrtf(sq*(1.0f/DIM) + 1e-5f);
  float* y = Y + (size_t)row * DIM;
#pragma unroll
  for (int i = 0; i < 5; ++i) {
    int c = lane + 64*i;
    y[c] = (v[i]-mean)*rstd*g[c] + bta[c];
  }
}

// ---------------- Tiled fp32 GEMM: C[M,N] = A[M,K(lda)] @ W[K,N(ldw)] (+bias)(+R) --
#define BM 64
#define BN 64
#define BK 16

__global__ __launch_bounds__(256) void gemm_kernel(
    const float* __restrict__ A, int lda,
    const float* __restrict__ W, int ldw,
    const float* __restrict__ bias,   // [N] or nullptr
    const float* __restrict__ R,      // residual [M,ldc] or nullptr
    float* __restrict__ C, int ldc,
    int M, int N, int K)
{
  __shared__ float As[BK][BM+4];
  __shared__ float Bs[BK][BN];
  int tid = threadIdx.x;
  int bm = blockIdx.y * BM;
  int bn = blockIdx.x * BN;
  int ar = tid >> 2;            // 0..63
  int ac = (tid & 3) << 2;      // 0,4,8,12
  int br = tid >> 4;            // 0..15
  int bc = (tid & 15) << 2;     // 0..60
  int tx = tid & 15, ty = tid >> 4;

  float acc[4][4];
#pragma unroll
  for (int i = 0; i < 4; ++i)
#pragma unroll
    for (int j = 0; j < 4; ++j) acc[i][j] = 0.f;

  const float* Aptr = A + (size_t)(bm + ar)*lda + ac;
  const float* Wptr = W + (size_t)br*ldw + bn + bc;

  for (int k0 = 0; k0 < K; k0 += BK) {
    float4 a4 = *(const float4*)(Aptr + k0);
    float4 b4 = *(const float4*)(Wptr + (size_t)k0*ldw);
    As[ac+0][ar] = a4.x; As[ac+1][ar] = a4.y;
    As[ac+2][ar] = a4.z; As[ac+3][ar] = a4.w;
    *(float4*)&Bs[br][bc] = b4;
    __syncthreads();
#pragma unroll
    for (int kk = 0; kk < BK; ++kk) {
      float4 av = *(const float4*)&As[kk][ty << 2];
      float4 bv = *(const float4*)&Bs[kk][tx << 2];
      float am[4] = {av.x, av.y, av.z, av.w};
      float bb[4] = {bv.x, bv.y, bv.z, bv.w};
#pragma unroll
      for (int i = 0; i < 4; ++i)
#pragma unroll
        for (int j = 0; j < 4; ++j)
          acc[i][j] = fmaf(am[i], bb[j], acc[i][j]);
    }
    __syncthreads();
  }

#pragma unroll
  for (int i = 0; i < 4; ++i) {
    int r = bm + (ty << 2) + i;
#pragma unroll
    for (int j = 0; j < 4; ++j) {
      int c = bn + (tx << 2) + j;
      float val = acc[i][j];
      if (bias) val += bias[c];
      if (R)    val += R[(size_t)r*ldc + c];
      C[(size_t)r*ldc + c] = val;
    }
  }
}

// ---------------- MFMA flash attention (bf16 compute, fp32 accum) ----------
// Grid (LQ/64, 16 bh, KSPLIT); block 256 = 4 waves; wave handles 16 q rows.
// Layouts (measured, m89/m91/m120): A[m=lane&15][k=quad*8+j],
// B[k=quad*8+j][n=lane&15], C/D[row=quad*4+reg][col=lane&15].
#define KS_STRIDE 72   // 32 rows x (64 padded D) +8 pad: 144B rows, 16B aligned
#define VS_STRIDE 40   // V^T: 48 d-rows x (32 k +8 pad): 80B rows, 16B aligned
#define PS_STRIDE 40   // P: 16 q-rows x (32 k +8 pad)

__global__ __launch_bounds__(256, 4) void attn_mfma(
    const float* __restrict__ Q, const float* __restrict__ K,
    const float* __restrict__ V,
    float* __restrict__ Pm, float* __restrict__ Pl, float* __restrict__ Pacc)
{
  __shared__ short smem[32*KS_STRIDE + 48*VS_STRIDE + 4*16*PS_STRIDE];
  short* Ks = smem;                         // [kk][d0..63(+pad)]
  short* Vs = smem + 32*KS_STRIDE;          // [d][kk] transposed
  int tid  = threadIdx.x;
  int w    = tid >> 6;
  int lane = tid & 63;
  int quad = lane >> 4;
  int n16  = lane & 15;
  short* Ps = Vs + 48*VS_STRIDE + w*16*PS_STRIDE;  // per-wave [q][kk]

  int qt = blockIdx.x, bh = blockIdx.y, ks = blockIdx.z;
  int b = bh >> 3, h = bh & 7;

  // zero the pad regions once (staging never writes them)
  for (int i = tid; i < 32*KS_STRIDE; i += 256) { if (i % KS_STRIDE >= 40) Ks[i] = 0; }
  for (int i = tid; i < 8*VS_STRIDE; i += 256) Vs[40*VS_STRIDE + i] = 0;

  // Q A-frags (pre-scaled by softmax scale * log2e, zero-padded D 40->64)
  const float lscale = 0.15811388300841897f * 1.4426950408889634f;
  int qi_a = qt*64 + w*16 + n16;            // A-layout row
  const float* qrow = Q + (size_t)(b*LQ + qi_a)*DIM + h*HD;
  bf16x8 qf0, qf1;
  {
    float4 f0 = *((const float4*)(qrow + quad*8));
    float4 f1 = *((const float4*)(qrow + quad*8) + 1);
    qf0[0]=f2bf(f0.x*lscale); qf0[1]=f2bf(f0.y*lscale);
    qf0[2]=f2bf(f0.z*lscale); qf0[3]=f2bf(f0.w*lscale);
    qf0[4]=f2bf(f1.x*lscale); qf0[5]=f2bf(f1.y*lscale);
    qf0[6]=f2bf(f1.z*lscale); qf0[7]=f2bf(f1.w*lscale);
    if (quad == 0) {
      float4 g0 = *((const float4*)(qrow + 32));
      float4 g1 = *((const float4*)(qrow + 36));
      qf1[0]=f2bf(g0.x*lscale); qf1[1]=f2bf(g0.y*lscale);
      qf1[2]=f2bf(g0.z*lscale); qf1[3]=f2bf(g0.w*lscale);
      qf1[4]=f2bf(g1.x*lscale); qf1[5]=f2bf(g1.y*lscale);
      qf1[6]=f2bf(g1.z*lscale); qf1[7]=f2bf(g1.w*lscale);
    } else {
      qf1 = bf16x8{0,0,0,0,0,0,0,0};
    }
  }

  const float* Kb = K + (size_t)b*LQ*DIM + h*HD;
  const float* Vb = V + (size_t)b*LQ*DIM + h*HD;
  int k0 = ks*KCHUNK;

  f32x4 o0 = {0.f,0.f,0.f,0.f}, o1 = o0, o2 = o0;
  float m[4], l[4];
#pragma unroll
  for (int r = 0; r < 4; ++r) { m[r] = -1e30f; l[r] = 0.f; }

  for (int t0 = 0; t0 < KCHUNK; t0 += KT) {
    __syncthreads();
    // stage 32 K-rows and 32 V-rows (V transposed) as bf16
#pragma unroll
    for (int i = 0; i < 5; ++i) {
      int f = i*256 + tid;              // 0..1279 = 32 rows x 40 cols
      int r = f / 40, c = f - r*40;
      size_t roff = (size_t)(k0 + t0 + r)*DIM + c;
      Ks[r*KS_STRIDE + c] = f2bf(Kb[roff]);
      Vs[c*VS_STRIDE + r] = f2bf(Vb[roff]);
    }
    __syncthreads();

    // QK^T: S[16q x 32k] in two C-frags
    f32x4 s0 = {0.f,0.f,0.f,0.f}, s1 = s0;
    {
      bf16x8 b00 = *(const bf16x8*)(Ks + (n16)*KS_STRIDE + quad*8);
      bf16x8 b01 = *(const bf16x8*)(Ks + (n16)*KS_STRIDE + 32 + quad*8);
      bf16x8 b10 = *(const bf16x8*)(Ks + (16+n16)*KS_STRIDE + quad*8);
      bf16x8 b11 = *(const bf16x8*)(Ks + (16+n16)*KS_STRIDE + 32 + quad*8);
      s0 = __builtin_amdgcn_mfma_f32_16x16x32_bf16(qf0, b00, s0, 0,0,0);
      s0 = __builtin_amdgcn_mfma_f32_16x16x32_bf16(qf1, b01, s0, 0,0,0);
      s1 = __builtin_amdgcn_mfma_f32_16x16x32_bf16(qf0, b10, s1, 0,0,0);
      s1 = __builtin_amdgcn_mfma_f32_16x16x32_bf16(qf1, b11, s1, 0,0,0);
    }

    // online softmax in C-layout: reg r is q-row quad*4+r
    float mx[4];
#pragma unroll
    for (int r = 0; r < 4; ++r) mx[r] = fmaxf(s0[r], s1[r]);
#pragma unroll
    for (int off = 1; off < 16; off <<= 1)
#pragma unroll
      for (int r = 0; r < 4; ++r)
        mx[r] = fmaxf(mx[r], __shfl_xor(mx[r], off, 64));

    f32x4 p0, p1;
    float co[4], rs[4];
#pragma unroll
    for (int r = 0; r < 4; ++r) {
      float mn = fmaxf(m[r], mx[r]);
      co[r] = exp2f(m[r] - mn);
      m[r] = mn;
      p0[r] = exp2f(s0[r] - mn);
      p1[r] = exp2f(s1[r] - mn);
      rs[r] = p0[r] + p1[r];
    }
#pragma unroll
    for (int off = 1; off < 16; off <<= 1)
#pragma unroll
      for (int r = 0; r < 4; ++r)
        rs[r] += __shfl_xor(rs[r], off, 64);
#pragma unroll
    for (int r = 0; r < 4; ++r) {
      l[r] = l[r]*co[r] + rs[r];
      o0[r] *= co[r]; o1[r] *= co[r]; o2[r] *= co[r];
    }

    // P: C-layout -> LDS -> A-layout (per-wave buffer, no barrier needed)
#pragma unroll
    for (int r = 0; r < 4; ++r) {
      int row = quad*4 + r;
      Ps[row*PS_STRIDE + n16]      = f2bf(p0[r]);
      Ps[row*PS_STRIDE + 16 + n16] = f2bf(p1[r]);
    }
    bf16x8 pa = *(const bf16x8*)(Ps + n16*PS_STRIDE + quad*8);

    // PV: O[16q x 48d(pad)] += P[16x32] @ V[32x48]
    bf16x8 v0 = *(const bf16x8*)(Vs + (n16)*VS_STRIDE + quad*8);
    bf16x8 v1 = *(const bf16x8*)(Vs + (16+n16)*VS_STRIDE + quad*8);
    bf16x8 v2 = *(const bf16x8*)(Vs + (32+n16)*VS_STRIDE + quad*8);
    o0 = __builtin_amdgcn_mfma_f32_16x16x32_bf16(pa, v0, o0, 0,0,0);
    o1 = __builtin_amdgcn_mfma_f32_16x16x32_bf16(pa, v1, o1, 0,0,0);
    o2 = __builtin_amdgcn_mfma_f32_16x16x32_bf16(pa, v2, o2, 0,0,0);
  }

  // write k-split partials (C-layout rows)
  int gqbase = bh*LQ + qt*64 + w*16 + quad*4;
  size_t base = (size_t)ks*NQROWS;
#pragma unroll
  for (int r = 0; r < 4; ++r) {
    size_t gq = base + gqbase + r;
    float* pw = Pacc + gq*40;
    pw[n16]      = o0[r];
    pw[16 + n16] = o1[r];
    if (n16 < 8) pw[32 + n16] = o2[r];
    if (n16 == 0) { Pm[gq] = m[r]; Pl[gq] = l[r]; }
  }
}

// Merge KSPLIT partials per q-row -> O
__global__ __launch_bounds__(256) void attn_merge(
    const float* __restrict__ Pm, const float* __restrict__ Pl,
    const float* __restrict__ Pacc, float* __restrict__ O)
{
  int idx = blockIdx.x*256 + threadIdx.x;   // 0..32767
  int bh = idx >> 11, qi = idx & (LQ-1);
  int b = bh >> 3, h = bh & 7;
  float m[KSPLIT], l[KSPLIT];
  float M = -1e30f;
#pragma unroll
  for (int k = 0; k < KSPLIT; ++k) {
    m[k] = Pm[(size_t)k*NQROWS + idx];
    l[k] = Pl[(size_t)k*NQROWS + idx];
    M = fmaxf(M, m[k]);
  }
  float c[KSPLIT], L = 0.f;
#pragma unroll
  for (int k = 0; k < KSPLIT; ++k) {
    c[k] = exp2f(m[k] - M);
    L += c[k]*l[k];
  }
  float inv = 1.0f / L;
  float* orow = O + (size_t)(b*LQ + qi)*DIM + h*HD;
#pragma unroll
  for (int u = 0; u < 10; ++u) {
    float4 o = make_float4(0.f, 0.f, 0.f, 0.f);
#pragma unroll
    for (int k = 0; k < KSPLIT; ++k) {
      float4 a = *((const float4*)(Pacc + ((size_t)k*NQROWS + idx)*40) + u);
      o.x = fmaf(c[k], a.x, o.x);
      o.y = fmaf(c[k], a.y, o.y);
      o.z = fmaf(c[k], a.z, o.z);
      o.w = fmaf(c[k], a.w, o.w);
    }
    o.x *= inv; o.y *= inv; o.z *= inv; o.w *= inv;
    *((float4*)orow + u) = o;
  }
}

// ---------------- GEGLU: proj[:, :1280] *= gelu_exact(proj[:, 1280:]) -------
__global__ __launch_bounds__(256) void geglu_kernel(float* __restrict__ proj)
{
  int idx = blockIdx.x * 256 + threadIdx.x;    // over MROWS * (FFD/4)
  int mrow = idx / (FFD/4);
  int j4   = idx - mrow*(FFD/4);
  float4* px = (float4*)(proj + (size_t)mrow*FF2) + j4;
  float4* pg = (float4*)(proj + (size_t)mrow*FF2 + FFD) + j4;
  float4 x = *px, g = *pg;
  const float k = 0.7071067811865476f;
  x.x *= 0.5f * g.x * (1.f + erff(g.x * k));
  x.y *= 0.5f * g.y * (1.f + erff(g.y * k));
  x.z *= 0.5f * g.z * (1.f + erff(g.z * k));
  x.w *= 0.5f * g.w * (1.f + erff(g.w * k));
  *px = x;
}

extern "C" void kernel_launch(void* const* d_in, const int* in_sizes, int n_in,
                              void* d_out, int out_size, void* d_ws, size_t ws_size,
                              hipStream_t stream) {
  const float* hidden = (const float*)d_in[0];
  // d_in[1] encoder_hidden_states: UNUSED (softmax rows sum to 1 -> cross == vH)
  const float* ln1_g = (const float*)d_in[2];
  const float* ln1_b = (const float*)d_in[3];
  const float* wq1   = (const float*)d_in[4];
  const float* wk1   = (const float*)d_in[5];
  const float* wv1   = (const float*)d_in[6];
  const float* wo1   = (const float*)d_in[7];
  const float* bo1   = (const float*)d_in[8];
  const float* ln2_g = (const float*)d_in[9];
  const float* ln2_b = (const float*)d_in[10];
  // d_in[11] wq2, d_in[12] wk2: UNUSED
  const float* wvh   = (const float*)d_in[13];
  const float* wo2   = (const float*)d_in[14];
  const float* bo2   = (const float*)d_in[15];
  const float* ln3_g = (const float*)d_in[16];
  const float* ln3_b = (const float*)d_in[17];
  const float* wff1  = (const float*)d_in[18];
  const float* bff1  = (const float*)d_in[19];
  const float* wff2  = (const float*)d_in[20];
  const float* bff2  = (const float*)d_in[21];
  float* out = (float*)d_out;

  float* ws = (float*)d_ws;
  const size_t NB = (size_t)MROWS * DIM;   // 1,310,720 floats
  float* buf0 = ws;            // ln out / attn out / ln3 out
  float* buf1 = buf0 + NB;     // q / ln2 out
  float* buf2 = buf1 + NB;     // k
  float* buf3 = buf2 + NB;     // v
  float* h1   = buf3 + NB;     // hidden after stage 1
  float* h2   = h1   + NB;     // hidden after stage 2
  float* Wc   = h2   + NB;     // wvh @ wo2, 320x320
  float* proj = Wc + (size_t)DIM*DIM;  // 4096 x 2560 (stage 3)

  // Attention k-split partials alias the proj region (disjoint lifetimes):
  float* Pm   = proj;                       // KSPLIT*32768
  float* Pl   = Pm + (size_t)KSPLIT*NQROWS;
  float* Pacc = Pl + (size_t)KSPLIT*NQROWS; // KSPLIT*32768*40

  dim3 t256(256);
  dim3 g320(DIM/BN, MROWS/BM);   // (5, 64)
  dim3 gwc(DIM/BN, DIM/BM);      // (5, 5)
  dim3 gff1(FF2/BN, MROWS/BM);   // (40, 64)
  dim3 gattn(LQ/64, BATCH*NH, KSPLIT);

  // Stage 1: self-attention
  ln_kernel<<<MROWS/4, t256, 0, stream>>>(hidden, ln1_g, ln1_b, buf0);
  gemm_kernel<<<g320, t256, 0, stream>>>(buf0, DIM, wq1, DIM, nullptr, nullptr, buf1, DIM, MROWS, DIM, DIM);
  gemm_kernel<<<g320, t256, 0, stream>>>(buf0, DIM, wk1, DIM, nullptr, nullptr, buf2, DIM, MROWS, DIM, DIM);
  gemm_kernel<<<g320, t256, 0, stream>>>(buf0, DIM, wv1, DIM, nullptr, nullptr, buf3, DIM, MROWS, DIM, DIM);
  attn_mfma<<<gattn, t256, 0, stream>>>(buf1, buf2, buf3, Pm, Pl, Pacc);
  attn_merge<<<NQROWS/256, t256, 0, stream>>>(Pm, Pl, Pacc, buf0);
  gemm_kernel<<<g320, t256, 0, stream>>>(buf0, DIM, wo1, DIM, bo1, hidden, h1, DIM, MROWS, DIM, DIM);

  // Stage 2: "cross-attention" == ln2(h1) @ (wvh @ wo2) + bo2 (softmax sums to 1)
  ln_kernel<<<MROWS/4, t256, 0, stream>>>(h1, ln2_g, ln2_b, buf1);
  gemm_kernel<<<gwc,  t256, 0, stream>>>(wvh, DIM, wo2, DIM, nullptr, nullptr, Wc, DIM, DIM, DIM, DIM);
  gemm_kernel<<<g320, t256, 0, stream>>>(buf1, DIM, Wc, DIM, bo2, h1, h2, DIM, MROWS, DIM, DIM);

  // Stage 3: GEGLU FF
  ln_kernel<<<MROWS/4, t256, 0, stream>>>(h2, ln3_g, ln3_b, buf0);
  gemm_kernel<<<gff1, t256, 0, stream>>>(buf0, DIM, wff1, FF2, bff1, nullptr, proj, FF2, MROWS, FF2, DIM);
  geglu_kernel<<<(MROWS*(FFD/4))/256, t256, 0, stream>>>(proj);
  gemm_kernel<<<g320, t256, 0, stream>>>(proj, FF2, wff2, DIM, bff2, h2, out, DIM, MROWS, DIM, FFD);
}

// Round 4
// 315.386 us; speedup vs baseline: 8.8013x; 1.7314x over previous
//
#include <hip/hip_runtime.h>
#include <math.h>

// Problem constants
#define DIM   320
#define HD    40
#define NH    8
#define LQ    2048
#define BATCH 2
#define MROWS 4096
#define FFD   1280
#define FF2   2560

#define KSPLIT 2
#define KCHUNK (LQ/KSPLIT) // 1024
#define KT     32
#define NQROWS (BATCH*NH*LQ)  // 32768

typedef unsigned short ushort_t;
using bf16x8 = __attribute__((ext_vector_type(8))) short;
using f32x4  = __attribute__((ext_vector_type(4))) float;

static __device__ inline ushort_t f2bf(float f) {
  union { float f; unsigned u; } x{f};
  unsigned r = x.u + 0x7FFFu + ((x.u >> 16) & 1u);
  return (ushort_t)(r >> 16);
}
static __device__ inline float bf2f(ushort_t h) {
  union { unsigned u; float f; } x; x.u = ((unsigned)h) << 16; return x.f;
}

// ---------------- LayerNorm: one wave per row of 320, bf16 out ----------------
__global__ __launch_bounds__(256) void ln_kernel(
    const float* __restrict__ X, const float* __restrict__ g,
    const float* __restrict__ bta, ushort_t* __restrict__ Y)
{
  int row  = blockIdx.x * 4 + (threadIdx.x >> 6);
  int lane = threadIdx.x & 63;
  const float* x = X + (size_t)row * DIM;
  float v[5];
  float s = 0.f;
#pragma unroll
  for (int i = 0; i < 5; ++i) { v[i] = x[lane + 64*i]; s += v[i]; }
#pragma unroll
  for (int off = 32; off >= 1; off >>= 1) s += __shfl_xor(s, off, 64);
  float mean = s * (1.0f/DIM);
  float sq = 0.f;
#pragma unroll
  for (int i = 0; i < 5; ++i) { float d = v[i] - mean; sq += d*d; }
#pragma unroll
  for (int off = 32; off >= 1; off >>= 1) sq += __shfl_xor(sq, off, 64);
  float rstd = rsqrtf(sq*(1.0f/DIM) + 1e-5f);
  ushort_t* y = Y + (size_t)row * DIM;
#pragma unroll
  for (int i = 0; i < 5; ++i) {
    int c = lane + 64*i;
    y[c] = f2bf((v[i]-mean)*rstd*g[c] + bta[c]);
  }
}

// ---------------- Weight convert/transpose to bf16, k-fastest -------------
// dst region layout (shorts): wqkvT[960][320] | wo1t[320][320] | wo2t[320][320]
//   | wff1t[2560][320] | wff2t[320][1280] | wvhb[320][320] (plain)
#define OFF_WQKVT 0
#define OFF_WO1T  (960*320)
#define OFF_WO2T  (OFF_WO1T + 320*320)
#define OFF_WFF1T (OFF_WO2T + 320*320)
#define OFF_WFF2T (OFF_WFF1T + 320*2560)
#define OFF_WVHB  (OFF_WFF2T + 1280*320)
#define WBF_TOTAL (OFF_WVHB + 320*320)

__global__ __launch_bounds__(256) void convw_kernel(
    const float* __restrict__ wq1, const float* __restrict__ wk1,
    const float* __restrict__ wv1, const float* __restrict__ wo1,
    const float* __restrict__ wo2, const float* __restrict__ wff1,
    const float* __restrict__ wff2, const float* __restrict__ wvh,
    ushort_t* __restrict__ dst)
{
  int e = blockIdx.y;
  const float* src; int K, N; size_t doff; int tr = 1;
  switch (e) {
    case 0: src=wq1;  K=320;  N=320;  doff=OFF_WQKVT;            break;
    case 1: src=wk1;  K=320;  N=320;  doff=OFF_WQKVT + 320*320;  break;
    case 2: src=wv1;  K=320;  N=320;  doff=OFF_WQKVT + 2*320*320;break;
    case 3: src=wo1;  K=320;  N=320;  doff=OFF_WO1T;             break;
    case 4: src=wo2;  K=320;  N=320;  doff=OFF_WO2T;             break;
    case 5: src=wff1; K=320;  N=2560; doff=OFF_WFF1T;            break;
    case 6: src=wff2; K=1280; N=320;  doff=OFF_WFF2T;            break;
    default: src=wvh; K=320;  N=320;  doff=OFF_WVHB; tr=0;       break;
  }
  int ntN = N/32;
  int nt_total = (K/32)*ntN;
  int t = blockIdx.x;
  if (t >= nt_total) return;
  int kt = t / ntN, nt = t - kt*ntN;
  __shared__ float tile[32][33];
  int tx = threadIdx.x & 31, ty = threadIdx.x >> 5;
  ushort_t* d = dst + doff;
#pragma unroll
  for (int i = 0; i < 4; ++i) {
    int r = ty + 8*i;
    tile[r][tx] = src[(size_t)(kt*32+r)*N + nt*32+tx];
  }
  __syncthreads();
  if (tr) {
#pragma unroll
    for (int i = 0; i < 4; ++i) {
      int r = ty + 8*i;   // n within tile
      d[(size_t)(nt*32+r)*K + kt*32+tx] = f2bf(tile[tx][r]);
    }
  } else {
#pragma unroll
    for (int i = 0; i < 4; ++i) {
      int r = ty + 8*i;
      d[(size_t)(kt*32+r)*N + nt*32+tx] = f2bf(tile[r][tx]);
    }
  }
}

// ---------------- bf16 MFMA GEMM (TN): C[M,N] = A[M,K] @ Bt[N,K]^T ---------
// block 256 = 4 waves (2x2), tile 64x64, BK=32. Both frags contiguous b128
// at 40-short LDS stride (20-dword => 2-way bank alias, free per m136).
#define AS_STRIDE 40
__global__ __launch_bounds__(256) void mgemm(
    const ushort_t* __restrict__ A, int lda,
    const ushort_t* __restrict__ Bt, int ldb,
    const float* __restrict__ bias,
    const float* __restrict__ R,
    float* __restrict__ Cf, ushort_t* __restrict__ Cb, int ldc,
    int K)
{
  __shared__ ushort_t As[64*AS_STRIDE];
  __shared__ ushort_t Bs[64*AS_STRIDE];
  int tid = threadIdx.x;
  int w = tid >> 6, lane = tid & 63, quad = lane >> 4, n16 = lane & 15;
  int wm = w >> 1, wn = w & 1;
  int bm = blockIdx.y * 64, bn = blockIdx.x * 64;
  int sr = tid >> 2, sc = (tid & 3) << 3;
  const ushort_t* Ag = A  + (size_t)(bm + sr)*lda + sc;
  const ushort_t* Bg = Bt + (size_t)(bn + sr)*ldb + sc;

  f32x4 acc00 = {0.f,0.f,0.f,0.f}, acc01 = acc00, acc10 = acc00, acc11 = acc00;

  for (int k0 = 0; k0 < K; k0 += 32) {
    float4 av = *(const float4*)(Ag + k0);
    float4 bv = *(const float4*)(Bg + k0);
    __syncthreads();
    *(float4*)(As + sr*AS_STRIDE + sc) = av;
    *(float4*)(Bs + sr*AS_STRIDE + sc) = bv;
    __syncthreads();
    bf16x8 fa0 = *(const bf16x8*)(As + (wm*32 +      n16)*AS_STRIDE + quad*8);
    bf16x8 fa1 = *(const bf16x8*)(As + (wm*32 + 16 + n16)*AS_STRIDE + quad*8);
    bf16x8 fb0 = *(const bf16x8*)(Bs + (wn*32 +      n16)*AS_STRIDE + quad*8);
    bf16x8 fb1 = *(const bf16x8*)(Bs + (wn*32 + 16 + n16)*AS_STRIDE + quad*8);
    acc00 = __builtin_amdgcn_mfma_f32_16x16x32_bf16(fa0, fb0, acc00, 0,0,0);
    acc01 = __builtin_amdgcn_mfma_f32_16x16x32_bf16(fa0, fb1, acc01, 0,0,0);
    acc10 = __builtin_amdgcn_mfma_f32_16x16x32_bf16(fa1, fb0, acc10, 0,0,0);
    acc11 = __builtin_amdgcn_mfma_f32_16x16x32_bf16(fa1, fb1, acc11, 0,0,0);
  }

  f32x4 accs[2][2] = {{acc00, acc01},{acc10, acc11}};
#pragma unroll
  for (int s = 0; s < 2; ++s)
#pragma unroll
    for (int t = 0; t < 2; ++t) {
      int c = bn + wn*32 + t*16 + n16;
      float bb = bias ? bias[c] : 0.f;
#pragma unroll
      for (int i = 0; i < 4; ++i) {
        int r = bm + wm*32 + s*16 + quad*4 + i;
        float v = accs[s][t][i] + bb;
        if (R)  v += R[(size_t)r*ldc + c];
        if (Cf) Cf[(size_t)r*ldc + c] = v;
        if (Cb) Cb[(size_t)r*ldc + c] = f2bf(v);
      }
    }
}

// ---------------- MFMA flash attention, bf16 QKV input ----------------
// qkv: bf16 [4096][960] = q|k|v per row. Grid (LQ/64, 16 bh, KSPLIT),
// block 256 = 4 waves; wave handles 16 q rows.
#define KS_STRIDE 72   // 36 dwords: frag-read bank stride 4r -> 2-way (free)
#define VS_STRIDE 40
#define PS_STRIDE 40

static __device__ inline int vswz(int d, int k) {
  return d*VS_STRIDE + ((((k>>3) ^ ((d>>3)&3)))<<3) + (k&7);
}

__global__ __launch_bounds__(256, 4) void attn_mfma(
    const ushort_t* __restrict__ qkv,
    float* __restrict__ Pm, float* __restrict__ Pl, float* __restrict__ Pacc)
{
  __shared__ ushort_t Ks[32*KS_STRIDE];
  __shared__ ushort_t Vs[48*VS_STRIDE];
  __shared__ ushort_t Ps[4*16*PS_STRIDE];
  int tid  = threadIdx.x;
  int w    = tid >> 6;
  int lane = tid & 63;
  int quad = lane >> 4;
  int n16  = lane & 15;
  ushort_t* Psw = Ps + w*16*PS_STRIDE;

  int qt = blockIdx.x, bh = blockIdx.y, ks = blockIdx.z;
  int b = bh >> 3, h = bh & 7;

  // zero pad regions once (K cols 40..71; V rows 40..47)
  for (int i = tid; i < 32*32; i += 256) { int r = i >> 5, c = i & 31; Ks[r*KS_STRIDE + 40 + c] = 0; }
  for (int i = tid; i < 8*VS_STRIDE; i += 256) Vs[40*VS_STRIDE + i] = 0;

  // Q A-frags straight from bf16 global (no conversion); scale folded into exp2
  const float lscale = 0.15811388300841897f * 1.4426950408889634f;
  const ushort_t* qrow = qkv + (size_t)(b*LQ + qt*64 + w*16 + n16)*960 + h*HD;
  bf16x8 qf0 = *(const bf16x8*)(qrow + quad*8);
  bf16x8 qf1 = (quad == 0) ? *(const bf16x8*)(qrow + 32) : bf16x8{0,0,0,0,0,0,0,0};

  const ushort_t* Kg = qkv + (size_t)(b*LQ)*960 + DIM     + h*HD;
  const ushort_t* Vg = qkv + (size_t)(b*LQ)*960 + 2*DIM   + h*HD;
  int k0 = ks*KCHUNK;

  f32x4 o0 = {0.f,0.f,0.f,0.f}, o1 = o0, o2 = o0;
  float m[4], l[4];
#pragma unroll
  for (int r = 0; r < 4; ++r) { m[r] = -1e30f; l[r] = 0.f; }

  for (int t0 = 0; t0 < KCHUNK; t0 += KT) {
    __syncthreads();
    // stage 32 K rows (dword copies) + 32 V rows (transposed, swizzled)
    const ushort_t* Kt = Kg + (size_t)(k0 + t0)*960;
    const ushort_t* Vt = Vg + (size_t)(k0 + t0)*960;
#pragma unroll
    for (int i = 0; i < 5; ++i) {
      int f = i*256 + tid;            // 1280 dword slots; wave-aligned split
      if (f < 640) {
        int r = f/20, c2 = f - r*20;
        unsigned u = *(const unsigned*)(Kt + (size_t)r*960 + c2*2);
        *(unsigned*)(Ks + r*KS_STRIDE + c2*2) = u;
      } else {
        int g = f - 640;
        int r = g/20, c2 = g - r*20;
        unsigned u = *(const unsigned*)(Vt + (size_t)r*960 + c2*2);
        int d0 = c2*2;
        Vs[vswz(d0,   r)] = (ushort_t)(u & 0xffffu);
        Vs[vswz(d0+1, r)] = (ushort_t)(u >> 16);
      }
    }
    __syncthreads();

    // QK^T: S[16q x 32k]
    f32x4 s0 = {0.f,0.f,0.f,0.f}, s1 = s0;
    {
      bf16x8 b00 = *(const bf16x8*)(Ks + (n16)*KS_STRIDE + quad*8);
      bf16x8 b01 = *(const bf16x8*)(Ks + (n16)*KS_STRIDE + 32 + quad*8);
      bf16x8 b10 = *(const bf16x8*)(Ks + (16+n16)*KS_STRIDE + quad*8);
      bf16x8 b11 = *(const bf16x8*)(Ks + (16+n16)*KS_STRIDE + 32 + quad*8);
      s0 = __builtin_amdgcn_mfma_f32_16x16x32_bf16(qf0, b00, s0, 0,0,0);
      s0 = __builtin_amdgcn_mfma_f32_16x16x32_bf16(qf1, b01, s0, 0,0,0);
      s1 = __builtin_amdgcn_mfma_f32_16x16x32_bf16(qf0, b10, s1, 0,0,0);
      s1 = __builtin_amdgcn_mfma_f32_16x16x32_bf16(qf1, b11, s1, 0,0,0);
    }

    // online softmax (base-2, scale folded here)
    float mx[4];
#pragma unroll
    for (int r = 0; r < 4; ++r) mx[r] = fmaxf(s0[r], s1[r]);
#pragma unroll
    for (int off = 1; off < 16; off <<= 1)
#pragma unroll
      for (int r = 0; r < 4; ++r)
        mx[r] = fmaxf(mx[r], __shfl_xor(mx[r], off, 64));

    f32x4 p0, p1;
    float co[4], rs[4];
#pragma unroll
    for (int r = 0; r < 4; ++r) {
      float mn = fmaxf(m[r], mx[r]*lscale);
      co[r] = exp2f(m[r] - mn);
      m[r] = mn;
      p0[r] = exp2f(s0[r]*lscale - mn);
      p1[r] = exp2f(s1[r]*lscale - mn);
      rs[r] = p0[r] + p1[r];
    }
#pragma unroll
    for (int off = 1; off < 16; off <<= 1)
#pragma unroll
      for (int r = 0; r < 4; ++r)
        rs[r] += __shfl_xor(rs[r], off, 64);
#pragma unroll
    for (int r = 0; r < 4; ++r) {
      l[r] = l[r]*co[r] + rs[r];
      o0[r] *= co[r]; o1[r] *= co[r]; o2[r] *= co[r];
    }

    // P: C-layout -> per-wave LDS -> A-layout
#pragma unroll
    for (int r = 0; r < 4; ++r) {
      int row = quad*4 + r;
      Psw[row*PS_STRIDE + n16]      = f2bf(p0[r]);
      Psw[row*PS_STRIDE + 16 + n16] = f2bf(p1[r]);
    }
    bf16x8 pa = *(const bf16x8*)(Psw + n16*PS_STRIDE + quad*8);

    // PV: O[16q x 48d] += P[16x32] @ V[32x48]  (V in [d][k] swizzled)
    bf16x8 v0 = *(const bf16x8*)(Vs + (n16)*VS_STRIDE      + ((quad ^ ((n16>>3)&3))<<3));
    bf16x8 v1 = *(const bf16x8*)(Vs + (16+n16)*VS_STRIDE   + ((quad ^ (((16+n16)>>3)&3))<<3));
    bf16x8 v2 = *(const bf16x8*)(Vs + (32+n16)*VS_STRIDE   + ((quad ^ (((32+n16)>>3)&3))<<3));
    o0 = __builtin_amdgcn_mfma_f32_16x16x32_bf16(pa, v0, o0, 0,0,0);
    o1 = __builtin_amdgcn_mfma_f32_16x16x32_bf16(pa, v1, o1, 0,0,0);
    o2 = __builtin_amdgcn_mfma_f32_16x16x32_bf16(pa, v2, o2, 0,0,0);
  }

  // k-split partials (fp32)
  int gqbase = bh*LQ + qt*64 + w*16 + quad*4;
  size_t base = (size_t)ks*NQROWS;
#pragma unroll
  for (int r = 0; r < 4; ++r) {
    size_t gq = base + gqbase + r;
    float* pw = Pacc + gq*40;
    pw[n16]      = o0[r];
    pw[16 + n16] = o1[r];
    if (n16 < 8) pw[32 + n16] = o2[r];
    if (n16 == 0) { Pm[gq] = m[r]; Pl[gq] = l[r]; }
  }
}

// Merge KSPLIT partials per q-row -> bf16 O [4096][320]
__global__ __launch_bounds__(256) void attn_merge(
    const float* __restrict__ Pm, const float* __restrict__ Pl,
    const float* __restrict__ Pacc, ushort_t* __restrict__ O)
{
  int idx = blockIdx.x*256 + threadIdx.x;   // 0..32767
  int bh = idx >> 11, qi = idx & (LQ-1);
  int b = bh >> 3, h = bh & 7;
  float m[KSPLIT], l[KSPLIT];
  float M = -1e30f;
#pragma unroll
  for (int k = 0; k < KSPLIT; ++k) {
    m[k] = Pm[(size_t)k*NQROWS + idx];
    l[k] = Pl[(size_t)k*NQROWS + idx];
    M = fmaxf(M, m[k]);
  }
  float c[KSPLIT], L = 0.f;
#pragma unroll
  for (int k = 0; k < KSPLIT; ++k) {
    c[k] = exp2f(m[k] - M);
    L += c[k]*l[k];
  }
  float inv = 1.0f / L;
  ushort_t* orow = O + (size_t)(b*LQ + qi)*DIM + h*HD;
#pragma unroll
  for (int u = 0; u < 10; ++u) {
    float4 o = make_float4(0.f, 0.f, 0.f, 0.f);
#pragma unroll
    for (int k = 0; k < KSPLIT; ++k) {
      float4 a = *((const float4*)(Pacc + ((size_t)k*NQROWS + idx)*40) + u);
      o.x = fmaf(c[k], a.x, o.x);
      o.y = fmaf(c[k], a.y, o.y);
      o.z = fmaf(c[k], a.z, o.z);
      o.w = fmaf(c[k], a.w, o.w);
    }
    unsigned lo = (unsigned)f2bf(o.x*inv) | ((unsigned)f2bf(o.y*inv) << 16);
    unsigned hi = (unsigned)f2bf(o.z*inv) | ((unsigned)f2bf(o.w*inv) << 16);
    *(unsigned*)(orow + 4*u)     = lo;
    *(unsigned*)(orow + 4*u + 2) = hi;
  }
}

// ---------------- GEGLU: bf16 in [4096][2560] -> bf16 out [4096][1280] -----
__global__ __launch_bounds__(256) void geglu_kernel(
    const ushort_t* __restrict__ proj, ushort_t* __restrict__ out)
{
  int idx = blockIdx.x*256 + threadIdx.x;   // over MROWS * 160
  int row = idx / 160, j8 = idx - row*160;
  const ushort_t* px = proj + (size_t)row*FF2 + j8*8;
  const ushort_t* pg = px + FFD;
  ushort_t xb[8], gb[8], ob[8];
  *(uint4*)xb = *(const uint4*)px;
  *(uint4*)gb = *(const uint4*)pg;
  const float kk = 0.7071067811865476f;
#pragma unroll
  for (int i = 0; i < 8; ++i) {
    float g = bf2f(gb[i]);
    float v = bf2f(xb[i]) * 0.5f * g * (1.f + erff(g * kk));
    ob[i] = f2bf(v);
  }
  *(uint4*)(out + (size_t)row*FFD + j8*8) = *(uint4*)ob;
}

extern "C" void kernel_launch(void* const* d_in, const int* in_sizes, int n_in,
                              void* d_out, int out_size, void* d_ws, size_t ws_size,
                              hipStream_t stream) {
  const float* hidden = (const float*)d_in[0];
  // d_in[1] encoder_hidden_states: UNUSED (softmax rows sum to 1 -> cross == vH)
  const float* ln1_g = (const float*)d_in[2];
  const float* ln1_b = (const float*)d_in[3];
  const float* wq1   = (const float*)d_in[4];
  const float* wk1   = (const float*)d_in[5];
  const float* wv1   = (const float*)d_in[6];
  const float* wo1   = (const float*)d_in[7];
  const float* bo1   = (const float*)d_in[8];
  const float* ln2_g = (const float*)d_in[9];
  const float* ln2_b = (const float*)d_in[10];
  // d_in[11] wq2, d_in[12] wk2: UNUSED
  const float* wvh   = (const float*)d_in[13];
  const float* wo2   = (const float*)d_in[14];
  const float* bo2   = (const float*)d_in[15];
  const float* ln3_g = (const float*)d_in[16];
  const float* ln3_b = (const float*)d_in[17];
  const float* wff1  = (const float*)d_in[18];
  const float* bff1  = (const float*)d_in[19];
  const float* wff2  = (const float*)d_in[20];
  const float* bff2  = (const float*)d_in[21];
  float* out = (float*)d_out;

  // workspace layout: bf16 region first (shorts), then fp32 region
  ushort_t* wsu = (ushort_t*)d_ws;
  ushort_t* wbf   = wsu;                         // weights, WBF_TOTAL shorts
  ushort_t* lnb   = wbf + WBF_TOTAL;             // 4096*320
  ushort_t* qkvb  = lnb + (size_t)MROWS*DIM;     // 4096*960
  ushort_t* attnb = qkvb + (size_t)MROWS*3*DIM;  // 4096*320
  ushort_t* projb = attnb + (size_t)MROWS*DIM;   // 4096*2560
  ushort_t* gegb  = projb + (size_t)MROWS*FF2;   // 4096*1280
  ushort_t* wct   = gegb + (size_t)MROWS*FFD;    // 320*320 (Wc^T, bf16)
  float* fws = (float*)(wct + 320*320 + 64);
  float* h1   = fws;                              // 4096*320
  float* h2   = h1 + (size_t)MROWS*DIM;
  float* Pm   = h2 + (size_t)MROWS*DIM;           // KSPLIT*32768
  float* Pl   = Pm + (size_t)KSPLIT*NQROWS;
  float* Pacc = Pl + (size_t)KSPLIT*NQROWS;       // KSPLIT*32768*40

  dim3 t256(256);
  dim3 gconv(800, 8);
  dim3 gqkv(15, 64);     // N=960
  dim3 g320(5, 64);      // N=320
  dim3 gwc(5, 5);        // 320x320
  dim3 gff1(40, 64);     // N=2560
  dim3 gattn(LQ/64, BATCH*NH, KSPLIT);

  // weight conversion/transposition (bf16, k-fastest)
  convw_kernel<<<gconv, t256, 0, stream>>>(wq1, wk1, wv1, wo1, wo2, wff1, wff2, wvh, wbf);

  // Stage 1: self-attention
  ln_kernel<<<MROWS/4, t256, 0, stream>>>(hidden, ln1_g, ln1_b, lnb);
  mgemm<<<gqkv, t256, 0, stream>>>(lnb, DIM, wbf + OFF_WQKVT, DIM, nullptr, nullptr,
                                   nullptr, qkvb, 3*DIM, DIM);
  attn_mfma<<<gattn, t256, 0, stream>>>(qkvb, Pm, Pl, Pacc);
  attn_merge<<<NQROWS/256, t256, 0, stream>>>(Pm, Pl, Pacc, attnb);
  mgemm<<<g320, t256, 0, stream>>>(attnb, DIM, wbf + OFF_WO1T, DIM, bo1, hidden,
                                   h1, nullptr, DIM, DIM);

  // Stage 2: cross == ln2(h1) @ (wvh@wo2) + bo2   (softmax sums to 1)
  ln_kernel<<<MROWS/4, t256, 0, stream>>>(h1, ln2_g, ln2_b, lnb);
  // Wc^T = wo2^T @ wvh^T : A = wo2t, Bt = wvh (plain bf16)
  mgemm<<<gwc, t256, 0, stream>>>(wbf + OFF_WO2T, DIM, wbf + OFF_WVHB, DIM,
                                  nullptr, nullptr, nullptr, wct, DIM, DIM);
  mgemm<<<g320, t256, 0, stream>>>(lnb, DIM, wct, DIM, bo2, h1,
                                   h2, nullptr, DIM, DIM);

  // Stage 3: GEGLU FF
  ln_kernel<<<MROWS/4, t256, 0, stream>>>(h2, ln3_g, ln3_b, lnb);
  mgemm<<<gff1, t256, 0, stream>>>(lnb, DIM, wbf + OFF_WFF1T, DIM, bff1, nullptr,
                                   nullptr, projb, FF2, DIM);
  geglu_kernel<<<(MROWS*160)/256, t256, 0, stream>>>(projb, gegb);
  mgemm<<<g320, t256, 0, stream>>>(gegb, FFD, wbf + OFF_WFF2T, FFD, bff2, h2,
                                   out, nullptr, DIM, FFD);
}

// Round 5
// 303.671 us; speedup vs baseline: 9.1408x; 1.0386x over previous
//
#include <hip/hip_runtime.h>
#include <math.h>

// Problem constants
#define DIM   320
#define HD    40
#define NH    8
#define LQ    2048
#define BATCH 2
#define MROWS 4096
#define FFD   1280
#define FF2   2560

#define KSPLIT 2
#define KCHUNK (LQ/KSPLIT) // 1024
#define KT     32
#define NQROWS (BATCH*NH*LQ)  // 32768

typedef unsigned short ushort_t;
using bf16x8 = __attribute__((ext_vector_type(8))) short;
using f32x4  = __attribute__((ext_vector_type(4))) float;

static __device__ inline ushort_t f2bf(float f) {
  union { float f; unsigned u; } x{f};
  unsigned r = x.u + 0x7FFFu + ((x.u >> 16) & 1u);
  return (ushort_t)(r >> 16);
}
static __device__ inline float bf2f(ushort_t h) {
  union { unsigned u; float f; } x; x.u = ((unsigned)h) << 16; return x.f;
}

// ---------------- LayerNorm: one wave per row of 320, bf16 out ----------------
__global__ __launch_bounds__(256) void ln_kernel(
    const float* __restrict__ X, const float* __restrict__ g,
    const float* __restrict__ bta, ushort_t* __restrict__ Y)
{
  int row  = blockIdx.x * 4 + (threadIdx.x >> 6);
  int lane = threadIdx.x & 63;
  const float* x = X + (size_t)row * DIM;
  float v[5];
  float s = 0.f;
#pragma unroll
  for (int i = 0; i < 5; ++i) { v[i] = x[lane + 64*i]; s += v[i]; }
#pragma unroll
  for (int off = 32; off >= 1; off >>= 1) s += __shfl_xor(s, off, 64);
  float mean = s * (1.0f/DIM);
  float sq = 0.f;
#pragma unroll
  for (int i = 0; i < 5; ++i) { float d = v[i] - mean; sq += d*d; }
#pragma unroll
  for (int off = 32; off >= 1; off >>= 1) sq += __shfl_xor(sq, off, 64);
  float rstd = rsqrtf(sq*(1.0f/DIM) + 1e-5f);
  ushort_t* y = Y + (size_t)row * DIM;
#pragma unroll
  for (int i = 0; i < 5; ++i) {
    int c = lane + 64*i;
    y[c] = f2bf((v[i]-mean)*rstd*g[c] + bta[c]);
  }
}

// ---------------- Weight convert/transpose to bf16, k-fastest -------------
#define OFF_WQKVT 0
#define OFF_WO1T  (960*320)
#define OFF_WO2T  (OFF_WO1T + 320*320)
#define OFF_WFF1T (OFF_WO2T + 320*320)
#define OFF_WFF2T (OFF_WFF1T + 320*2560)
#define OFF_WVHB  (OFF_WFF2T + 1280*320)
#define WBF_TOTAL (OFF_WVHB + 320*320)

__global__ __launch_bounds__(256) void convw_kernel(
    const float* __restrict__ wq1, const float* __restrict__ wk1,
    const float* __restrict__ wv1, const float* __restrict__ wo1,
    const float* __restrict__ wo2, const float* __restrict__ wff1,
    const float* __restrict__ wff2, const float* __restrict__ wvh,
    ushort_t* __restrict__ dst)
{
  int e = blockIdx.y;
  const float* src; int K, N; size_t doff; int tr = 1;
  switch (e) {
    case 0: src=wq1;  K=320;  N=320;  doff=OFF_WQKVT;            break;
    case 1: src=wk1;  K=320;  N=320;  doff=OFF_WQKVT + 320*320;  break;
    case 2: src=wv1;  K=320;  N=320;  doff=OFF_WQKVT + 2*320*320;break;
    case 3: src=wo1;  K=320;  N=320;  doff=OFF_WO1T;             break;
    case 4: src=wo2;  K=320;  N=320;  doff=OFF_WO2T;             break;
    case 5: src=wff1; K=320;  N=2560; doff=OFF_WFF1T;            break;
    case 6: src=wff2; K=1280; N=320;  doff=OFF_WFF2T;            break;
    default: src=wvh; K=320;  N=320;  doff=OFF_WVHB; tr=0;       break;
  }
  int ntN = N/32;
  int nt_total = (K/32)*ntN;
  int t = blockIdx.x;
  if (t >= nt_total) return;
  int kt = t / ntN, nt = t - kt*ntN;
  __shared__ float tile[32][33];
  int tx = threadIdx.x & 31, ty = threadIdx.x >> 5;
  ushort_t* d = dst + doff;
#pragma unroll
  for (int i = 0; i < 4; ++i) {
    int r = ty + 8*i;
    tile[r][tx] = src[(size_t)(kt*32+r)*N + nt*32+tx];
  }
  __syncthreads();
  if (tr) {
#pragma unroll
    for (int i = 0; i < 4; ++i) {
      int r = ty + 8*i;
      d[(size_t)(nt*32+r)*K + kt*32+tx] = f2bf(tile[tx][r]);
    }
  } else {
#pragma unroll
    for (int i = 0; i < 4; ++i) {
      int r = ty + 8*i;
      d[(size_t)(kt*32+r)*N + nt*32+tx] = f2bf(tile[r][tx]);
    }
  }
}

// ---- V transpose: qkv v-section [4096][960] -> Vt[bh=16][48][2048], pad 0 --
__global__ __launch_bounds__(256) void vt_kernel(
    const ushort_t* __restrict__ qkv, ushort_t* __restrict__ Vt)
{
  int bh = blockIdx.y;          // 0..15
  int kt = blockIdx.x;          // 0..31 (k-chunk of 64)
  int b = bh >> 3, h = bh & 7;
  __shared__ ushort_t tile[64*42];   // [k][d], stride 42 shorts
  int tid = threadIdx.x;
  const ushort_t* src = qkv + (size_t)(b*LQ + kt*64)*960 + 2*DIM + h*HD;
#pragma unroll
  for (int i = 0; i < 5; ++i) {       // 64 rows x 20 dwords
    int f = i*256 + tid;
    int r = f/20, c2 = f - r*20;
    *(unsigned*)(tile + r*42 + c2*2) = *(const unsigned*)(src + (size_t)r*960 + c2*2);
  }
  __syncthreads();
  ushort_t* dstp = Vt + (size_t)bh*48*2048 + kt*64;
#pragma unroll
  for (int i = 0; i < 6; ++i) {       // 48 d-rows x 32 dwords
    int f = i*256 + tid;
    int dd = f >> 5, kk = f & 31;
    unsigned val = 0;
    if (dd < 40) {
      unsigned lo = tile[(kk*2)*42 + dd];
      unsigned hi = tile[(kk*2+1)*42 + dd];
      val = lo | (hi << 16);
    }
    *(unsigned*)(dstp + (size_t)dd*2048 + kk*2) = val;
  }
}

// ---------------- bf16 MFMA GEMM (TN) with register prefetch ---------------
#define AS_STRIDE 40
__global__ __launch_bounds__(256) void mgemm(
    const ushort_t* __restrict__ A, int lda,
    const ushort_t* __restrict__ Bt, int ldb,
    const float* __restrict__ bias,
    const float* __restrict__ R,
    float* __restrict__ Cf, ushort_t* __restrict__ Cb, int ldc,
    int K)
{
  __shared__ ushort_t As[64*AS_STRIDE];
  __shared__ ushort_t Bs[64*AS_STRIDE];
  int tid = threadIdx.x;
  int w = tid >> 6, lane = tid & 63, quad = lane >> 4, n16 = lane & 15;
  int wm = w >> 1, wn = w & 1;
  int bm = blockIdx.y * 64, bn = blockIdx.x * 64;
  int sr = tid >> 2, sc = (tid & 3) << 3;
  const ushort_t* Ag = A  + (size_t)(bm + sr)*lda + sc;
  const ushort_t* Bg = Bt + (size_t)(bn + sr)*ldb + sc;

  f32x4 acc00 = {0.f,0.f,0.f,0.f}, acc01 = acc00, acc10 = acc00, acc11 = acc00;

  float4 av = *(const float4*)(Ag);
  float4 bv = *(const float4*)(Bg);
  for (int k0 = 0; k0 < K; k0 += 32) {
    __syncthreads();
    *(float4*)(As + sr*AS_STRIDE + sc) = av;
    *(float4*)(Bs + sr*AS_STRIDE + sc) = bv;
    __syncthreads();
    if (k0 + 32 < K) {              // prefetch next tile while computing this
      av = *(const float4*)(Ag + k0 + 32);
      bv = *(const float4*)(Bg + k0 + 32);
    }
    bf16x8 fa0 = *(const bf16x8*)(As + (wm*32 +      n16)*AS_STRIDE + quad*8);
    bf16x8 fa1 = *(const bf16x8*)(As + (wm*32 + 16 + n16)*AS_STRIDE + quad*8);
    bf16x8 fb0 = *(const bf16x8*)(Bs + (wn*32 +      n16)*AS_STRIDE + quad*8);
    bf16x8 fb1 = *(const bf16x8*)(Bs + (wn*32 + 16 + n16)*AS_STRIDE + quad*8);
    acc00 = __builtin_amdgcn_mfma_f32_16x16x32_bf16(fa0, fb0, acc00, 0,0,0);
    acc01 = __builtin_amdgcn_mfma_f32_16x16x32_bf16(fa0, fb1, acc01, 0,0,0);
    acc10 = __builtin_amdgcn_mfma_f32_16x16x32_bf16(fa1, fb0, acc10, 0,0,0);
    acc11 = __builtin_amdgcn_mfma_f32_16x16x32_bf16(fa1, fb1, acc11, 0,0,0);
  }

  f32x4 accs[2][2] = {{acc00, acc01},{acc10, acc11}};
#pragma unroll
  for (int s = 0; s < 2; ++s)
#pragma unroll
    for (int t = 0; t < 2; ++t) {
      int c = bn + wn*32 + t*16 + n16;
      float bb = bias ? bias[c] : 0.f;
#pragma unroll
      for (int i = 0; i < 4; ++i) {
        int r = bm + wm*32 + s*16 + quad*4 + i;
        float v = accs[s][t][i] + bb;
        if (R)  v += R[(size_t)r*ldc + c];
        if (Cf) Cf[(size_t)r*ldc + c] = v;
        if (Cb) Cb[(size_t)r*ldc + c] = f2bf(v);
      }
    }
}

// ---------------- MFMA flash attention: barrier-free, direct-global frags --
// qkv bf16 [4096][960] (q|k|v); Vt bf16 [16][48][2048] pre-transposed.
// Grid (LQ/64, 16 bh, KSPLIT); block 256 = 4 waves; wave owns 16 q-rows.
// K B-frag == global K layout (lane reads K[n16][quad*8..+7], 16B).
// V B-frag == Vt rows (lane reads Vt[d=n16+16f][k0+t0+quad*8..+7], 16B).
// Only LDS use: per-wave P C->A layout round-trip (wave-internal, no barrier).
#define PS_STRIDE 40

__global__ __launch_bounds__(256, 2) void attn_mfma(
    const ushort_t* __restrict__ qkv, const ushort_t* __restrict__ Vt,
    float* __restrict__ Pm, float* __restrict__ Pl, float* __restrict__ Pacc)
{
  __shared__ ushort_t Ps[4*16*PS_STRIDE];
  int tid  = threadIdx.x;
  int w    = tid >> 6;
  int lane = tid & 63;
  int quad = lane >> 4;
  int n16  = lane & 15;
  ushort_t* Psw = Ps + w*16*PS_STRIDE;

  int qt = blockIdx.x, bh = blockIdx.y, ks = blockIdx.z;
  int b = bh >> 3, h = bh & 7;

  const float lscale = 0.15811388300841897f * 1.4426950408889634f;
  const ushort_t* qrow = qkv + (size_t)(b*LQ + qt*64 + w*16 + n16)*960 + h*HD;
  bf16x8 qf0 = *(const bf16x8*)(qrow + quad*8);
  bf16x8 qf1 = (quad == 0) ? *(const bf16x8*)(qrow + 32) : bf16x8{0,0,0,0,0,0,0,0};

  const ushort_t* Kg = qkv + (size_t)b*LQ*960 + DIM + h*HD;   // K section
  const ushort_t* Vh = Vt + (size_t)bh*48*2048;
  int k0 = ks*KCHUNK;

  f32x4 o0 = {0.f,0.f,0.f,0.f}, o1 = o0, o2 = o0;
  float m[4], l[4];
#pragma unroll
  for (int r = 0; r < 4; ++r) { m[r] = -1e30f; l[r] = 0.f; }

  for (int t0 = 0; t0 < KCHUNK; t0 += KT) {
    const ushort_t* Ktp = Kg + (size_t)(k0 + t0)*960;
    // K B-frags straight from global (16B contiguous per lane)
    bf16x8 kb00 = *(const bf16x8*)(Ktp + (size_t)n16*960 + quad*8);
    bf16x8 kb10 = *(const bf16x8*)(Ktp + (size_t)(16+n16)*960 + quad*8);
    bf16x8 kb01 = (quad == 0) ? *(const bf16x8*)(Ktp + (size_t)n16*960 + 32)
                              : bf16x8{0,0,0,0,0,0,0,0};
    bf16x8 kb11 = (quad == 0) ? *(const bf16x8*)(Ktp + (size_t)(16+n16)*960 + 32)
                              : bf16x8{0,0,0,0,0,0,0,0};

    f32x4 s0 = {0.f,0.f,0.f,0.f}, s1 = s0;
    s0 = __builtin_amdgcn_mfma_f32_16x16x32_bf16(qf0, kb00, s0, 0,0,0);
    s0 = __builtin_amdgcn_mfma_f32_16x16x32_bf16(qf1, kb01, s0, 0,0,0);
    s1 = __builtin_amdgcn_mfma_f32_16x16x32_bf16(qf0, kb10, s1, 0,0,0);
    s1 = __builtin_amdgcn_mfma_f32_16x16x32_bf16(qf1, kb11, s1, 0,0,0);

    // V B-frags from pre-transposed Vt (16B contiguous per lane)
    bf16x8 v0 = *(const bf16x8*)(Vh + (size_t)(n16)*2048    + k0 + t0 + quad*8);
    bf16x8 v1 = *(const bf16x8*)(Vh + (size_t)(16+n16)*2048 + k0 + t0 + quad*8);
    bf16x8 v2 = *(const bf16x8*)(Vh + (size_t)(32+n16)*2048 + k0 + t0 + quad*8);

    // online softmax (base-2, scale folded)
    float mx[4];
#pragma unroll
    for (int r = 0; r < 4; ++r) mx[r] = fmaxf(s0[r], s1[r]);
#pragma unroll
    for (int off = 1; off < 16; off <<= 1)
#pragma unroll
      for (int r = 0; r < 4; ++r)
        mx[r] = fmaxf(mx[r], __shfl_xor(mx[r], off, 64));

    f32x4 p0, p1;
    float co[4], rs[4];
#pragma unroll
    for (int r = 0; r < 4; ++r) {
      float mn = fmaxf(m[r], mx[r]*lscale);
      co[r] = exp2f(m[r] - mn);
      m[r] = mn;
      p0[r] = exp2f(s0[r]*lscale - mn);
      p1[r] = exp2f(s1[r]*lscale - mn);
      rs[r] = p0[r] + p1[r];
    }
#pragma unroll
    for (int off = 1; off < 16; off <<= 1)
#pragma unroll
      for (int r = 0; r < 4; ++r)
        rs[r] += __shfl_xor(rs[r], off, 64);
#pragma unroll
    for (int r = 0; r < 4; ++r) {
      l[r] = l[r]*co[r] + rs[r];
      o0[r] *= co[r]; o1[r] *= co[r]; o2[r] *= co[r];
    }

    // P: C-layout -> per-wave LDS -> A-layout (wave-internal ordering only)
#pragma unroll
    for (int r = 0; r < 4; ++r) {
      int row = quad*4 + r;
      Psw[row*PS_STRIDE + n16]      = f2bf(p0[r]);
      Psw[row*PS_STRIDE + 16 + n16] = f2bf(p1[r]);
    }
    bf16x8 pa = *(const bf16x8*)(Psw + n16*PS_STRIDE + quad*8);

    o0 = __builtin_amdgcn_mfma_f32_16x16x32_bf16(pa, v0, o0, 0,0,0);
    o1 = __builtin_amdgcn_mfma_f32_16x16x32_bf16(pa, v1, o1, 0,0,0);
    o2 = __builtin_amdgcn_mfma_f32_16x16x32_bf16(pa, v2, o2, 0,0,0);
  }

  // k-split partials (fp32)
  int gqbase = bh*LQ + qt*64 + w*16 + quad*4;
  size_t base = (size_t)ks*NQROWS;
#pragma unroll
  for (int r = 0; r < 4; ++r) {
    size_t gq = base + gqbase + r;
    float* pw = Pacc + gq*40;
    pw[n16]      = o0[r];
    pw[16 + n16] = o1[r];
    if (n16 < 8) pw[32 + n16] = o2[r];
    if (n16 == 0) { Pm[gq] = m[r]; Pl[gq] = l[r]; }
  }
}

// Merge KSPLIT partials per q-row -> bf16 O [4096][320]
__global__ __launch_bounds__(256) void attn_merge(
    const float* __restrict__ Pm, const float* __restrict__ Pl,
    const float* __restrict__ Pacc, ushort_t* __restrict__ O)
{
  int idx = blockIdx.x*256 + threadIdx.x;   // 0..32767
  int bh = idx >> 11, qi = idx & (LQ-1);
  int b = bh >> 3, h = bh & 7;
  float m[KSPLIT], l[KSPLIT];
  float M = -1e30f;
#pragma unroll
  for (int k = 0; k < KSPLIT; ++k) {
    m[k] = Pm[(size_t)k*NQROWS + idx];
    l[k] = Pl[(size_t)k*NQROWS + idx];
    M = fmaxf(M, m[k]);
  }
  float c[KSPLIT], L = 0.f;
#pragma unroll
  for (int k = 0; k < KSPLIT; ++k) {
    c[k] = exp2f(m[k] - M);
    L += c[k]*l[k];
  }
  float inv = 1.0f / L;
  ushort_t* orow = O + (size_t)(b*LQ + qi)*DIM + h*HD;
#pragma unroll
  for (int u = 0; u < 10; ++u) {
    float4 o = make_float4(0.f, 0.f, 0.f, 0.f);
#pragma unroll
    for (int k = 0; k < KSPLIT; ++k) {
      float4 a = *((const float4*)(Pacc + ((size_t)k*NQROWS + idx)*40) + u);
      o.x = fmaf(c[k], a.x, o.x);
      o.y = fmaf(c[k], a.y, o.y);
      o.z = fmaf(c[k], a.z, o.z);
      o.w = fmaf(c[k], a.w, o.w);
    }
    unsigned lo = (unsigned)f2bf(o.x*inv) | ((unsigned)f2bf(o.y*inv) << 16);
    unsigned hi = (unsigned)f2bf(o.z*inv) | ((unsigned)f2bf(o.w*inv) << 16);
    *(unsigned*)(orow + 4*u)     = lo;
    *(unsigned*)(orow + 4*u + 2) = hi;
  }
}

// ---------------- GEGLU: bf16 in [4096][2560] -> bf16 out [4096][1280] -----
__global__ __launch_bounds__(256) void geglu_kernel(
    const ushort_t* __restrict__ proj, ushort_t* __restrict__ out)
{
  int idx = blockIdx.x*256 + threadIdx.x;   // over MROWS * 160
  int row = idx / 160, j8 = idx - row*160;
  const ushort_t* px = proj + (size_t)row*FF2 + j8*8;
  const ushort_t* pg = px + FFD;
  ushort_t xb[8], gb[8], ob[8];
  *(uint4*)xb = *(const uint4*)px;
  *(uint4*)gb = *(const uint4*)pg;
  const float kk = 0.7071067811865476f;
#pragma unroll
  for (int i = 0; i < 8; ++i) {
    float g = bf2f(gb[i]);
    float v = bf2f(xb[i]) * 0.5f * g * (1.f + erff(g * kk));
    ob[i] = f2bf(v);
  }
  *(uint4*)(out + (size_t)row*FFD + j8*8) = *(uint4*)ob;
}

extern "C" void kernel_launch(void* const* d_in, const int* in_sizes, int n_in,
                              void* d_out, int out_size, void* d_ws, size_t ws_size,
                              hipStream_t stream) {
  const float* hidden = (const float*)d_in[0];
  // d_in[1] encoder_hidden_states: UNUSED (softmax rows sum to 1 -> cross == vH)
  const float* ln1_g = (const float*)d_in[2];
  const float* ln1_b = (const float*)d_in[3];
  const float* wq1   = (const float*)d_in[4];
  const float* wk1   = (const float*)d_in[5];
  const float* wv1   = (const float*)d_in[6];
  const float* wo1   = (const float*)d_in[7];
  const float* bo1   = (const float*)d_in[8];
  const float* ln2_g = (const float*)d_in[9];
  const float* ln2_b = (const float*)d_in[10];
  // d_in[11] wq2, d_in[12] wk2: UNUSED
  const float* wvh   = (const float*)d_in[13];
  const float* wo2   = (const float*)d_in[14];
  const float* bo2   = (const float*)d_in[15];
  const float* ln3_g = (const float*)d_in[16];
  const float* ln3_b = (const float*)d_in[17];
  const float* wff1  = (const float*)d_in[18];
  const float* bff1  = (const float*)d_in[19];
  const float* wff2  = (const float*)d_in[20];
  const float* bff2  = (const float*)d_in[21];
  float* out = (float*)d_out;

  // workspace layout: bf16 region first (shorts), then fp32 region
  ushort_t* wsu = (ushort_t*)d_ws;
  ushort_t* wbf   = wsu;                         // weights, WBF_TOTAL shorts
  ushort_t* lnb   = wbf + WBF_TOTAL;             // 4096*320
  ushort_t* qkvb  = lnb + (size_t)MROWS*DIM;     // 4096*960
  ushort_t* attnb = qkvb + (size_t)MROWS*3*DIM;  // 4096*320
  ushort_t* projb = attnb + (size_t)MROWS*DIM;   // 4096*2560
  ushort_t* gegb  = projb + (size_t)MROWS*FF2;   // 4096*1280
  ushort_t* wct   = gegb + (size_t)MROWS*FFD;    // 320*320 (Wc^T, bf16)
  ushort_t* vtb   = wct + 320*320;               // Vt: 16*48*2048
  float* fws = (float*)(vtb + (size_t)16*48*2048 + 64);
  float* h1   = fws;                              // 4096*320
  float* h2   = h1 + (size_t)MROWS*DIM;
  float* Pm   = h2 + (size_t)MROWS*DIM;           // KSPLIT*32768
  float* Pl   = Pm + (size_t)KSPLIT*NQROWS;
  float* Pacc = Pl + (size_t)KSPLIT*NQROWS;       // KSPLIT*32768*40

  dim3 t256(256);
  dim3 gconv(800, 8);
  dim3 gqkv(15, 64);     // N=960
  dim3 g320(5, 64);      // N=320
  dim3 gwc(5, 5);        // 320x320
  dim3 gff1(40, 64);     // N=2560
  dim3 gvt(32, 16);
  dim3 gattn(LQ/64, BATCH*NH, KSPLIT);

  // weight conversion/transposition (bf16, k-fastest)
  convw_kernel<<<gconv, t256, 0, stream>>>(wq1, wk1, wv1, wo1, wo2, wff1, wff2, wvh, wbf);

  // Stage 1: self-attention
  ln_kernel<<<MROWS/4, t256, 0, stream>>>(hidden, ln1_g, ln1_b, lnb);
  mgemm<<<gqkv, t256, 0, stream>>>(lnb, DIM, wbf + OFF_WQKVT, DIM, nullptr, nullptr,
                                   nullptr, qkvb, 3*DIM, DIM);
  vt_kernel<<<gvt, t256, 0, stream>>>(qkvb, vtb);
  attn_mfma<<<gattn, t256, 0, stream>>>(qkvb, vtb, Pm, Pl, Pacc);
  attn_merge<<<NQROWS/256, t256, 0, stream>>>(Pm, Pl, Pacc, attnb);
  mgemm<<<g320, t256, 0, stream>>>(attnb, DIM, wbf + OFF_WO1T, DIM, bo1, hidden,
                                   h1, nullptr, DIM, DIM);

  // Stage 2: cross == ln2(h1) @ (wvh@wo2) + bo2   (softmax sums to 1)
  ln_kernel<<<MROWS/4, t256, 0, stream>>>(h1, ln2_g, ln2_b, lnb);
  mgemm<<<gwc, t256, 0, stream>>>(wbf + OFF_WO2T, DIM, wbf + OFF_WVHB, DIM,
                                  nullptr, nullptr, nullptr, wct, DIM, DIM);
  mgemm<<<g320, t256, 0, stream>>>(lnb, DIM, wct, DIM, bo2, h1,
                                   h2, nullptr, DIM, DIM);

  // Stage 3: GEGLU FF
  ln_kernel<<<MROWS/4, t256, 0, stream>>>(h2, ln3_g, ln3_b, lnb);
  mgemm<<<gff1, t256, 0, stream>>>(lnb, DIM, wbf + OFF_WFF1T, DIM, bff1, nullptr,
                                   nullptr, projb, FF2, DIM);
  geglu_kernel<<<(MROWS*160)/256, t256, 0, stream>>>(projb, gegb);
  mgemm<<<g320, t256, 0, stream>>>(gegb, FFD, wbf + OFF_WFF2T, FFD, bff2, h2,
                                   out, nullptr, DIM, FFD);
}